// Round 12
// baseline (2180.661 us; speedup 1.0000x reference)
//
#include <hip/hip_runtime.h>

typedef __bf16 bf16x8 __attribute__((ext_vector_type(8)));
typedef float f32x4 __attribute__((ext_vector_type(4)));

#define DEVI __device__ __forceinline__

namespace {
constexpr int cB = 4, cS = 2048, cD = 1024, cH = 2048, cL = 6;
constexpr int cM = cB * cS;                  // 8192 rows
constexpr float cEPS = 1.1920929e-07f;       // torch float32 eps
constexpr int NCH = 16, CHS = cS / NCH;      // scan chunks: 16 x 128
}

DEVI unsigned short f2bf(float f) {
  union { float f; unsigned u; } c; c.f = f;
  const unsigned u = c.u;
  return (unsigned short)((u + 0x7fffu + ((u >> 16) & 1u)) >> 16);  // RNE
}
DEVI float bf2f(unsigned short h) {
  union { unsigned u; float f; } c; c.u = ((unsigned)h) << 16;
  return c.f;
}

DEVI void gld16(const void* g, void* l) {
  __builtin_amdgcn_global_load_lds(
      (__attribute__((address_space(1))) void*)g,
      (__attribute__((address_space(3))) void*)l, 16, 0, 0);
}

union F4 { float4 v; float a[4]; };

// ---------------- embedding gather ----------------
__global__ __launch_bounds__(256) void embed_k(const int* __restrict__ x,
    const float* __restrict__ emb, float* __restrict__ xe) {
  const int bs = blockIdx.x;
  const int idx = x[bs];
  const int t = threadIdx.x;
  *(float4*)&xe[(size_t)bs * cD + t * 4] =
      *(const float4*)&emb[(size_t)idx * cD + t * 4];
}

// ------------- depthwise conv (K=3, SAME) + bias -> bf16 ----------
__global__ __launch_bounds__(256) void dwconv_k(const float* __restrict__ xe,
    const float* __restrict__ w, const float* __restrict__ bias,
    unsigned short* __restrict__ out) {
  const int bs = blockIdx.x;
  const int s = bs & (cS - 1);
  const int t = threadIdx.x;
  const int d = t * 4;
  const size_t base = (size_t)bs * cD + d;
  F4 x0, xm, xp, vb;
  x0.v = *(const float4*)&xe[base];
  xm.v = make_float4(0.f, 0.f, 0.f, 0.f);
  xp.v = make_float4(0.f, 0.f, 0.f, 0.f);
  if (s > 0) xm.v = *(const float4*)&xe[base - cD];
  if (s < cS - 1) xp.v = *(const float4*)&xe[base + cD];
  vb.v = *(const float4*)&bias[d];
  unsigned short o[4];
#pragma unroll
  for (int j = 0; j < 4; ++j) {
    const float w0 = w[(d + j) * 3 + 0];
    const float w1 = w[(d + j) * 3 + 1];
    const float w2 = w[(d + j) * 3 + 2];
    o[j] = f2bf(xm.a[j] * w0 + x0.a[j] * w1 + xp.a[j] * w2 + vb.a[j]);
  }
  *(ushort4*)&out[base] = make_ushort4(o[0], o[1], o[2], o[3]);
}

// ---------------- RMSNorm row (D=1024) -> bf16 ----------------
__global__ __launch_bounds__(256) void rmsnorm_k(const float* __restrict__ x,
    const float* __restrict__ w, unsigned short* __restrict__ o) {
  const int row = blockIdx.x;
  const int t = threadIdx.x;
  const size_t base = (size_t)row * cD + t * 4;
  F4 v; v.v = *(const float4*)&x[base];
  float ss = v.a[0]*v.a[0] + v.a[1]*v.a[1] + v.a[2]*v.a[2] + v.a[3]*v.a[3];
#pragma unroll
  for (int off = 32; off > 0; off >>= 1) ss += __shfl_down(ss, off, 64);
  __shared__ float red[4];
  if ((t & 63) == 0) red[t >> 6] = ss;
  __syncthreads();
  const float scale = rsqrtf((red[0]+red[1]+red[2]+red[3]) * (1.f/cD) + cEPS);
  F4 wv; wv.v = *(const float4*)&w[t * 4];
  *(ushort4*)&o[base] = make_ushort4(
      f2bf(v.a[0]*scale*wv.a[0]), f2bf(v.a[1]*scale*wv.a[1]),
      f2bf(v.a[2]*scale*wv.a[2]), f2bf(v.a[3]*scale*wv.a[3]));
}

// ------- merged weight convert: all 5 plain f32->bf16 tensors, one grid ----
__global__ __launch_bounds__(256) void wcvt_k(
    const float* __restrict__ s0, unsigned short* __restrict__ d0,   // pw
    const float* __restrict__ s1, unsigned short* __restrict__ d1,   // o
    const float* __restrict__ s2, unsigned short* __restrict__ d2,   // f1
    const float* __restrict__ s3, unsigned short* __restrict__ d3,   // f2
    const float* __restrict__ s4, unsigned short* __restrict__ d4) { // ow
  constexpr size_t nPW = (size_t)cL * cD * cD;
  constexpr size_t nHD = (size_t)cL * cD * cH;
  constexpr size_t b0 = nPW, b1 = b0 + nHD, b2 = b1 + nHD, b3 = b2 + nHD;
  constexpr size_t total = b3 + (size_t)cH * cD;
  const size_t i = ((size_t)blockIdx.x * 256 + threadIdx.x) * 4;
  if (i >= total) return;
  const float* s; unsigned short* d; size_t off;
  if (i < b0)      { s = s0; d = d0; off = i; }
  else if (i < b1) { s = s1; d = d1; off = i - b0; }
  else if (i < b2) { s = s2; d = d2; off = i - b1; }
  else if (i < b3) { s = s3; d = d3; off = i - b2; }
  else             { s = s4; d = d4; off = i - b3; }
  F4 v; v.v = *(const float4*)&s[off];
  *(ushort4*)&d[off] = make_ushort4(f2bf(v.a[0]), f2bf(v.a[1]),
                                    f2bf(v.a[2]), f2bf(v.a[3]));
}

// ------- interleave convert: dst rows (2r, 2r+1) = bf16(wz row r, wh row r) -
__global__ __launch_bounds__(256) void cvti2_k(const float* __restrict__ wz,
    const float* __restrict__ wh, unsigned short* __restrict__ d) {
  const size_t i = ((size_t)blockIdx.x * 256 + threadIdx.x) * 4;
  const int l = (int)(i >> 21);
  const int r = (int)((i >> 10) & (cH - 1));
  const int c = (int)(i & (cD - 1));
  F4 a, b; a.v = *(const float4*)&wz[i]; b.v = *(const float4*)&wh[i];
  const size_t dz = (((size_t)l * 2 * cH) + 2 * r) * cD + c;
  *(ushort4*)&d[dz] = make_ushort4(f2bf(a.a[0]), f2bf(a.a[1]),
                                   f2bf(a.a[2]), f2bf(a.a[3]));
  *(ushort4*)&d[dz + cD] = make_ushort4(f2bf(b.a[0]), f2bf(b.a[1]),
                                        f2bf(b.a[2]), f2bf(b.a[3]));
}

// ------- bias interleave: dst[l][2h]=bz, dst[l][2h+1]=bh (f32) -------------
__global__ __launch_bounds__(256) void biasi2_k(const float* __restrict__ bz,
    const float* __restrict__ bh, float* __restrict__ d) {
  const int i = blockIdx.x * 256 + threadIdx.x;   // cL*cH
  const int l = i >> 11, h = i & (cH - 1);
  d[((size_t)l * 2 * cH) + 2 * h]     = bz[i];
  d[((size_t)l * 2 * cH) + 2 * h + 1] = bh[i];
}

// shared phase sync/end for the 8-phase kernel
#define PH_SYNC()                                                           \
  __builtin_amdgcn_s_barrier();                                             \
  asm volatile("s_waitcnt lgkmcnt(0)" ::: "memory");                        \
  __builtin_amdgcn_sched_barrier(0);                                        \
  __builtin_amdgcn_s_setprio(1)

#define PH_END()                                                            \
  __builtin_amdgcn_s_setprio(0);                                            \
  __builtin_amdgcn_s_barrier()

// ======== unified 256x128 8-phase GEMM (T2 3-bit swizzle + counted vmcnt) ==
// C[M,N] = A[M,K]*W[N,K]^T + bias. BM=256, BN=128.
// Ledger (verified R11): reads 10/2/8/0; stages ph1:A(T+1,h1)->OBUF,
// ph3:B(T+2)->BUF, ph4:A(T+2,h0)->BUF; steady vmcnt(4); peeled tail vmcnt(0).
// EPI: 0 = f32 direct; 1 = f32 residual RMW; 4 = gelu->bf16 (LDS bounce);
//      6 = interleaved z|htil -> sigmoid/plain, de-interleaved bf16 stores
//          (width N/2) + FUSED scan1 -> Ac/Bc.
#define RDA_N(BUF, MH)                                                      \
  _Pragma("unroll") for (int mf = 0; mf < 4; ++mf)                          \
  _Pragma("unroll") for (int kk = 0; kk < 2; ++kk)                          \
      a[mf * 2 + kk] = *(const bf16x8*)&lds[(BUF)*16384 + aB + (MH)*4096 +  \
                                            mf * 1024 + ((kk) ? ck1 : ck0)];

#define RDB_N(BUF, NH)                                                      \
  _Pragma("unroll") for (int kk = 0; kk < 2; ++kk)                          \
      b[NH][kk] = *(const bf16x8*)&lds[32768 + (BUF)*8192 + bB +            \
                                       (NH)*1024 + ((kk) ? ck1 : ck0)];

#define MMQ_N(MH, NH)                                                       \
  _Pragma("unroll") for (int mf = 0; mf < 4; ++mf)                          \
  _Pragma("unroll") for (int kk = 0; kk < 2; ++kk)                          \
      acc[(MH)*4 + mf][NH] = __builtin_amdgcn_mfma_f32_16x16x32_bf16(       \
          a[mf * 2 + kk], b[NH][kk], acc[(MH)*4 + mf][NH], 0, 0, 0);

#define TILE_N(TI, BUF, OBUF, S1, S2, VM)                                   \
  {                                                                         \
    RDA_N(BUF, 0); RDB_N(BUF, 0);                                           \
    if (S1) { stA((TI) + 1, 1, ldsA(OBUF, 1)); }                            \
    PH_SYNC(); MMQ_N(0, 0); PH_END();                                       \
    RDB_N(BUF, 1);                                                          \
    PH_SYNC(); MMQ_N(0, 1); PH_END();                                       \
    RDA_N(BUF, 1);                                                          \
    if (S2) { stB((TI) + 2, ldsB(BUF)); }                                   \
    PH_SYNC(); MMQ_N(1, 1); PH_END();                                       \
    if (S2) { stA((TI) + 2, 0, ldsA(BUF, 0)); }                             \
    if (VM == 4) { asm volatile("s_waitcnt vmcnt(4)" ::: "memory"); }       \
    else         { asm volatile("s_waitcnt vmcnt(0)" ::: "memory"); }       \
    PH_SYNC(); MMQ_N(1, 0); PH_END();                                       \
  }

template<int N, int K, int EPI>
__global__ __launch_bounds__(512, 2) void gemm8(
    const unsigned short* __restrict__ A,
    const unsigned short* __restrict__ W,
    const float* __restrict__ bias,
    float* __restrict__ Cf, unsigned short* __restrict__ Cb,
    unsigned short* __restrict__ Cb2,
    float* __restrict__ Ac, float* __restrict__ Bc) {
  static_assert(K % 128 == 0, "NT must be even");
  constexpr int NT = K / 64;
  // LDS (ushort): A[buf] at buf*16384 (256x64); B[buf] at 32768+buf*8192
  // (128x64). 96 KiB; epilogue reuses as [256][128] bounce (64 KiB).
  __shared__ unsigned short lds[49152];
  const int t = threadIdx.x;
  const int lane = t & 63;
  const int wave = t >> 6;
  const int wr = wave >> 2;   // M half (128 rows)
  const int wc = wave & 3;    // N quarter (32 cols)
  const int m0 = blockIdx.x * 256;
  const int n0 = blockIdx.y * 128;

  const int srow = t >> 3;
  const int scol = (((t & 7) ^ ((t >> 3) & 7)) * 8);   // 3-bit T2 key
  const unsigned short* gA = A + (size_t)(m0 + srow) * K + scol;
  const unsigned short* gB = W + (size_t)(n0 + srow) * K + scol;
  const int ldsw = wave * 512;

  auto ldsA = [&](int buf, int h) -> unsigned short* {
    return (unsigned short*)&lds[buf * 16384 + h * 8192 + ldsw];
  };
  auto ldsB = [&](int buf) -> unsigned short* {
    return (unsigned short*)&lds[32768 + buf * 8192 + ldsw];
  };
  auto stA = [&](int tile, int h, unsigned short* dst) {
    const unsigned short* s = gA + (size_t)(h * 128) * K + tile * 64;
    gld16(s, dst);
    gld16(s + (size_t)64 * K, dst + 4096);
  };
  auto stB = [&](int tile, unsigned short* dst) {
    const unsigned short* s = gB + (size_t)tile * 64;
    gld16(s, dst);
    gld16(s + (size_t)64 * K, dst + 4096);
  };

  const int swz = (lane & 7) << 3;
  const int ck0 = ((lane >> 4) * 8) ^ swz;
  const int ck1 = (32 + (lane >> 4) * 8) ^ swz;
  const int aB = wr * 8192 + (lane & 15) * 64;
  const int bB = wc * 2048 + (lane & 15) * 64;

  bf16x8 a[8];
  bf16x8 b[2][2];
  f32x4 acc[8][2] = {};

  // prologue: A0 full + B0; {A1h0, B1} left in flight (A1h1 staged at ph1)
  stA(0, 0, ldsA(0, 0)); stA(0, 1, ldsA(0, 1));
  stB(0, ldsB(0));
  stA(1, 0, ldsA(1, 0));
  stB(1, ldsB(1));
  asm volatile("s_waitcnt vmcnt(4)" ::: "memory");
  __builtin_amdgcn_s_barrier();

  for (int tp = 0; tp < NT / 2 - 1; ++tp) {
    const int t0 = 2 * tp;
    TILE_N(t0, 0, 1, 1, 1, 4);
    TILE_N(t0 + 1, 1, 0, 1, 1, 4);
  }
  TILE_N(NT - 2, 0, 1, 1, 0, 0);
  TILE_N(NT - 1, 1, 0, 0, 0, 0);

  // ---- epilogue ----
  const int r0l = wr * 128 + ((lane >> 4) << 2);   // local row base 0..255
  const int c0l = wc * 32 + (lane & 15);           // local col base 0..127
  if constexpr (EPI <= 1) {
    // f32 paths: 64B-contiguous per 16 lanes, direct
    const int r0 = m0 + r0l;
    const int c0 = n0 + c0l;
#pragma unroll
    for (int mfg = 0; mfg < 8; ++mfg)
#pragma unroll
      for (int nfg = 0; nfg < 2; ++nfg) {
        const int col = c0 + nfg * 16;
        const float bv = bias[col];
#pragma unroll
        for (int r = 0; r < 4; ++r) {
          const size_t idx = (size_t)(r0 + mfg * 16 + r) * N + col;
          const float v = acc[mfg][nfg][r] + bv;
          if constexpr (EPI == 1) Cf[idx] += v;
          else                    Cf[idx] = v;
        }
      }
  } else {
    // bf16 paths: activation -> swizzled LDS [256][128] -> coalesced stores
    const bool isz = ((lane & 1) == 0);   // EPI==6: even global col = z
#pragma unroll
    for (int mfg = 0; mfg < 8; ++mfg)
#pragma unroll
      for (int nfg = 0; nfg < 2; ++nfg) {
        const int col = c0l + nfg * 16;
        const float bv = bias[n0 + col];
#pragma unroll
        for (int r = 0; r < 4; ++r) {
          const float v = acc[mfg][nfg][r] + bv;
          unsigned short o;
          if constexpr (EPI == 4) {
            o = f2bf(0.5f * v * (1.f + erff(v * 0.70710678118654752f)));
          } else {  // EPI == 6
            o = isz ? f2bf(1.f / (1.f + __expf(-v))) : f2bf(v);
          }
          const int rr = r0l + mfg * 16 + r;
          lds[rr * 128 + (col ^ (((rr >> 2) & 3) << 4))] = o;
        }
      }
    __syncthreads();
    if constexpr (EPI == 4) {
#pragma unroll
      for (int it = 0; it < 8; ++it) {
        const int flat = it * 512 + t;       // 256 rows x 16 chunks
        const int row = flat >> 4;
        const int ch = flat & 15;
        const float4 v = *(const float4*)&lds[row * 128 +
                                              ((ch * 8) ^ (((row >> 2) & 3) << 4))];
        *(float4*)&Cb[(size_t)(m0 + row) * N + n0 + ch * 8] = v;
      }
    } else {  // EPI == 6: de-interleave to Cb (z) / Cb2 (htil), width N/2
#pragma unroll
      for (int it = 0; it < 8; ++it) {
        const int flat = it * 512 + t;
        const int row = flat >> 4;
        const int ch = flat & 15;
        union { float4 v; unsigned u[4]; } q;
        q.v = *(const float4*)&lds[row * 128 +
                                   ((ch * 8) ^ (((row >> 2) & 3) << 4))];
        const ushort4 zz = make_ushort4(q.u[0] & 0xffff, q.u[1] & 0xffff,
                                        q.u[2] & 0xffff, q.u[3] & 0xffff);
        const ushort4 hh = make_ushort4(q.u[0] >> 16, q.u[1] >> 16,
                                        q.u[2] >> 16, q.u[3] >> 16);
        const size_t o = (size_t)(m0 + row) * (N / 2) + (n0 >> 1) + ch * 4;
        *(ushort4*)&Cb[o]  = zz;
        *(ushort4*)&Cb2[o] = hh;
      }
      // fused scan1: tile = 2 chunks (CHS=128 rows) x 64 h-channels
      if (t < 128) {
        const int lc = t >> 6;          // chunk half within tile
        const int lh = t & 63;          // local h
        float av = 1.f, bv = 0.f;
        const int s0 = lc * 128;
#pragma unroll 4
        for (int s = 0; s < CHS; ++s) {
          const int sr = s0 + s;
          const int c = (2 * lh) ^ (((sr >> 2) & 3) << 4);
          const unsigned w2 = *(const unsigned*)&lds[sr * 128 + c];
          const float zv = bf2f((unsigned short)(w2 & 0xffff));
          const float hv = bf2f((unsigned short)(w2 >> 16));
          const float aa = 1.f - zv;
          bv = aa * bv + zv * hv;
          av *= aa;
        }
        const int bidx = m0 / cS;
        const int ck = ((m0 & (cS - 1)) >> 7) + lc;
        const int hg = (n0 >> 1) + lh;
        const size_t so = ((size_t)bidx * NCH + ck) * cH + hg;
        Ac[so] = av;
        Bc[so] = bv;
      }
    }
  }
}

// fused scan2+scan3: per-thread prefix from chunk summaries, then replay;
// ck == NCH-1 threads emit h_next. (vectorized: 4 bf16 / 8B per lane)
__global__ __launch_bounds__(256) void scan23_k(const unsigned short* __restrict__ z,
    unsigned short* __restrict__ ht, const float* __restrict__ Ac,
    const float* __restrict__ Bc, const float* __restrict__ h_prev,
    float* __restrict__ hn, int l) {
  const int tid = blockIdx.x * 256 + threadIdx.x;
  const int hq = (tid & (cH / 4 - 1)) * 4;
  const int ck = (tid / (cH / 4)) & (NCH - 1);
  const int b = tid / ((cH / 4) * NCH);
  const size_t hoff = ((size_t)b * cL + l) * cH + hq;
  F4 h0; h0.v = *(const float4*)&h_prev[hoff];
  float r[4] = {h0.a[0], h0.a[1], h0.a[2], h0.a[3]};
  for (int c = 0; c < ck; ++c) {           // block-uniform trip count
    const size_t so = ((size_t)b * NCH + c) * cH + hq;
    F4 av, bv;
    av.v = *(const float4*)&Ac[so];
    bv.v = *(const float4*)&Bc[so];
#pragma unroll
    for (int j = 0; j < 4; ++j) r[j] = av.a[j] * r[j] + bv.a[j];
  }
  const size_t base = ((size_t)b * cS + (size_t)ck * CHS) * cH + hq;
#pragma unroll 4
  for (int s = 0; s < CHS; ++s) {
    const ushort4 zz = *(const ushort4*)&z[base + (size_t)s * cH];
    const ushort4 hh = *(const ushort4*)&ht[base + (size_t)s * cH];
    const float zf[4] = {bf2f(zz.x), bf2f(zz.y), bf2f(zz.z), bf2f(zz.w)};
    const float hf[4] = {bf2f(hh.x), bf2f(hh.y), bf2f(hh.z), bf2f(hh.w)};
#pragma unroll
    for (int j = 0; j < 4; ++j) r[j] = (1.f - zf[j]) * r[j] + zf[j] * hf[j];
    *(ushort4*)&ht[base + (size_t)s * cH] =
        make_ushort4(f2bf(r[0]), f2bf(r[1]), f2bf(r[2]), f2bf(r[3]));
  }
  if (ck == NCH - 1)
    *(float4*)&hn[hoff] = make_float4(r[0], r[1], r[2], r[3]);
}

extern "C" void kernel_launch(void* const* d_in, const int* in_sizes, int n_in,
                              void* d_out, int out_size, void* d_ws, size_t ws_size,
                              hipStream_t stream) {
  (void)in_sizes; (void)n_in; (void)out_size; (void)ws_size;
  const int*   x      = (const int*)d_in[0];
  const float* h_prev = (const float*)d_in[1];
  const float* emb    = (const float*)d_in[2];
  const float* cdw_w  = (const float*)d_in[3];
  const float* cdw_b  = (const float*)d_in[4];
  const float* cpw_w  = (const float*)d_in[5];
  const float* cpw_b  = (const float*)d_in[6];
  const float* n1w    = (const float*)d_in[7];
  const float* wzp    = (const float*)d_in[8];
  const float* bzp    = (const float*)d_in[9];
  const float* whp    = (const float*)d_in[10];
  const float* bhp    = (const float*)d_in[11];
  const float* wop    = (const float*)d_in[12];
  const float* bop    = (const float*)d_in[13];
  const float* n2w    = (const float*)d_in[14];
  const float* f1wp   = (const float*)d_in[15];
  const float* f1bp   = (const float*)d_in[16];
  const float* f2wp   = (const float*)d_in[17];
  const float* f2bp   = (const float*)d_in[18];
  const float* nw     = (const float*)d_in[19];
  const float* owp    = (const float*)d_in[20];
  const float* obp    = (const float*)d_in[21];

  float* out_main = (float*)d_out;                  // (B,S,H) f32
  float* out_hn   = out_main + (size_t)cM * cH;     // (B,L,H) f32

  char* p = (char*)d_ws;
  auto alloc = [&](size_t bytes) {
    char* r = p; p += (bytes + 255) & ~(size_t)255; return r;
  };
  float*          xe = (float*)alloc((size_t)cM * cD * 4);
  unsigned short* xn = (unsigned short*)alloc((size_t)cM * cD * 2);
  unsigned short* zb = (unsigned short*)alloc((size_t)cM * cH * 2);
  unsigned short* hb = (unsigned short*)alloc((size_t)cM * cH * 2);
  float* Ac = (float*)alloc((size_t)cB * NCH * cH * 4);
  float* Bc = (float*)alloc((size_t)cB * NCH * cH * 4);
  // all-layer bf16 weights (hoisted conversion)
  unsigned short* w_pw = (unsigned short*)alloc((size_t)cL * cD * cD * 2);
  unsigned short* w_zh = (unsigned short*)alloc((size_t)cL * 2 * cH * cD * 2);
  float*          bzh  = (float*)alloc((size_t)cL * 2 * cH * 4);
  unsigned short* w_o  = (unsigned short*)alloc((size_t)cL * cD * cH * 2);
  unsigned short* w_f1 = (unsigned short*)alloc((size_t)cL * cH * cD * 2);
  unsigned short* w_f2 = (unsigned short*)alloc((size_t)cL * cD * cH * 2);
  unsigned short* w_ow = (unsigned short*)alloc((size_t)cH * cD * 2);

  // merged weight prep: 3 dispatches total
  {
    constexpr size_t total = (size_t)cL * cD * cD + 3 * (size_t)cL * cD * cH +
                             (size_t)cH * cD;
    wcvt_k<<<dim3((unsigned)(total / 1024)), 256, 0, stream>>>(
        cpw_w, w_pw, wop, w_o, f1wp, w_f1, f2wp, w_f2, owp, w_ow);
    cvti2_k<<<dim3(cL * cH * cD / 1024), 256, 0, stream>>>(wzp, whp, w_zh);
    biasi2_k<<<dim3(cL * cH / 256), 256, 0, stream>>>(bzp, bhp, bzh);
  }

  embed_k<<<cM, 256, 0, stream>>>(x, emb, xe);

  for (int l = 0; l < cL; ++l) {
    const size_t oDD = (size_t)l * cD * cD, oHD = (size_t)l * cH * cD;

    // conv block: xe += pw(dwconv(xe)) + b
    dwconv_k<<<cM, 256, 0, stream>>>(xe, cdw_w + (size_t)l * cD * 3,
                                     cdw_b + (size_t)l * cD, xn);
    gemm8<cD, cD, 1><<<dim3(cM / 256, cD / 128), 512, 0, stream>>>(
        xn, w_pw + oDD, cpw_b + (size_t)l * cD, xe, nullptr, nullptr,
        nullptr, nullptr);

    // minGRU block: interleaved z|htil GEMM with fused scan1
    rmsnorm_k<<<cM, 256, 0, stream>>>(xe, n1w + (size_t)l * cD, xn);
    gemm8<2 * cH, cD, 6><<<dim3(cM / 256, 2 * cH / 128), 512, 0, stream>>>(
        xn, w_zh + (size_t)l * 2 * cH * cD, bzh + (size_t)l * 2 * cH,
        nullptr, zb, hb, Ac, Bc);
    scan23_k<<<cB * NCH * (cH / 4) / 256, 256, 0, stream>>>(zb, hb, Ac, Bc,
                                                            h_prev, out_hn, l);
    gemm8<cD, cH, 1><<<dim3(cM / 256, cD / 128), 512, 0, stream>>>(
        hb, w_o + oHD, bop + (size_t)l * cD, xe, nullptr, nullptr,
        nullptr, nullptr);

    // FFN block
    rmsnorm_k<<<cM, 256, 0, stream>>>(xe, n2w + (size_t)l * cD, xn);
    gemm8<cH, cD, 4><<<dim3(cM / 256, cH / 128), 512, 0, stream>>>(
        xn, w_f1 + oHD, f1bp + (size_t)l * cH, nullptr, zb, nullptr,
        nullptr, nullptr);
    gemm8<cD, cH, 1><<<dim3(cM / 256, cD / 128), 512, 0, stream>>>(
        zb, w_f2 + oHD, f2bp + (size_t)l * cD, xe, nullptr, nullptr,
        nullptr, nullptr);
  }

  rmsnorm_k<<<cM, 256, 0, stream>>>(xe, nw, xn);
  gemm8<cH, cD, 0><<<dim3(cM / 256, cH / 128), 512, 0, stream>>>(
      xn, w_ow, obp, out_main, nullptr, nullptr, nullptr, nullptr);
}

// Round 13
// 1997.407 us; speedup vs baseline: 1.0917x; 1.0917x over previous
//
#include <hip/hip_runtime.h>

typedef __bf16 bf16x8 __attribute__((ext_vector_type(8)));
typedef float f32x4 __attribute__((ext_vector_type(4)));

#define DEVI __device__ __forceinline__

namespace {
constexpr int cB = 4, cS = 2048, cD = 1024, cH = 2048, cL = 6;
constexpr int cM = cB * cS;                  // 8192 rows
constexpr float cEPS = 1.1920929e-07f;       // torch float32 eps
constexpr int NCH = 16, CHS = cS / NCH;      // scan chunks: 16 x 128
}

DEVI unsigned short f2bf(float f) {
  union { float f; unsigned u; } c; c.f = f;
  const unsigned u = c.u;
  return (unsigned short)((u + 0x7fffu + ((u >> 16) & 1u)) >> 16);  // RNE
}
DEVI float bf2f(unsigned short h) {
  union { unsigned u; float f; } c; c.u = ((unsigned)h) << 16;
  return c.f;
}

DEVI void gld16(const void* g, void* l) {
  __builtin_amdgcn_global_load_lds(
      (__attribute__((address_space(1))) void*)g,
      (__attribute__((address_space(3))) void*)l, 16, 0, 0);
}

union F4 { float4 v; float a[4]; };

// ---------------- embedding gather ----------------
__global__ __launch_bounds__(256) void embed_k(const int* __restrict__ x,
    const float* __restrict__ emb, float* __restrict__ xe) {
  const int bs = blockIdx.x;
  const int idx = x[bs];
  const int t = threadIdx.x;
  *(float4*)&xe[(size_t)bs * cD + t * 4] =
      *(const float4*)&emb[(size_t)idx * cD + t * 4];
}

// ------------- depthwise conv (K=3, SAME) + bias -> bf16 ----------
__global__ __launch_bounds__(256) void dwconv_k(const float* __restrict__ xe,
    const float* __restrict__ w, const float* __restrict__ bias,
    unsigned short* __restrict__ out) {
  const int bs = blockIdx.x;
  const int s = bs & (cS - 1);
  const int t = threadIdx.x;
  const int d = t * 4;
  const size_t base = (size_t)bs * cD + d;
  F4 x0, xm, xp, vb;
  x0.v = *(const float4*)&xe[base];
  xm.v = make_float4(0.f, 0.f, 0.f, 0.f);
  xp.v = make_float4(0.f, 0.f, 0.f, 0.f);
  if (s > 0) xm.v = *(const float4*)&xe[base - cD];
  if (s < cS - 1) xp.v = *(const float4*)&xe[base + cD];
  vb.v = *(const float4*)&bias[d];
  unsigned short o[4];
#pragma unroll
  for (int j = 0; j < 4; ++j) {
    const float w0 = w[(d + j) * 3 + 0];
    const float w1 = w[(d + j) * 3 + 1];
    const float w2 = w[(d + j) * 3 + 2];
    o[j] = f2bf(xm.a[j] * w0 + x0.a[j] * w1 + xp.a[j] * w2 + vb.a[j]);
  }
  *(ushort4*)&out[base] = make_ushort4(o[0], o[1], o[2], o[3]);
}

// ---------------- RMSNorm row (D=1024) -> bf16 ----------------
__global__ __launch_bounds__(256) void rmsnorm_k(const float* __restrict__ x,
    const float* __restrict__ w, unsigned short* __restrict__ o) {
  const int row = blockIdx.x;
  const int t = threadIdx.x;
  const size_t base = (size_t)row * cD + t * 4;
  F4 v; v.v = *(const float4*)&x[base];
  float ss = v.a[0]*v.a[0] + v.a[1]*v.a[1] + v.a[2]*v.a[2] + v.a[3]*v.a[3];
#pragma unroll
  for (int off = 32; off > 0; off >>= 1) ss += __shfl_down(ss, off, 64);
  __shared__ float red[4];
  if ((t & 63) == 0) red[t >> 6] = ss;
  __syncthreads();
  const float scale = rsqrtf((red[0]+red[1]+red[2]+red[3]) * (1.f/cD) + cEPS);
  F4 wv; wv.v = *(const float4*)&w[t * 4];
  *(ushort4*)&o[base] = make_ushort4(
      f2bf(v.a[0]*scale*wv.a[0]), f2bf(v.a[1]*scale*wv.a[1]),
      f2bf(v.a[2]*scale*wv.a[2]), f2bf(v.a[3]*scale*wv.a[3]));
}

// ------- merged weight convert: all 5 plain f32->bf16 tensors, one grid ----
__global__ __launch_bounds__(256) void wcvt_k(
    const float* __restrict__ s0, unsigned short* __restrict__ d0,   // pw
    const float* __restrict__ s1, unsigned short* __restrict__ d1,   // o
    const float* __restrict__ s2, unsigned short* __restrict__ d2,   // f1
    const float* __restrict__ s3, unsigned short* __restrict__ d3,   // f2
    const float* __restrict__ s4, unsigned short* __restrict__ d4) { // ow
  constexpr size_t nPW = (size_t)cL * cD * cD;
  constexpr size_t nHD = (size_t)cL * cD * cH;
  constexpr size_t b0 = nPW, b1 = b0 + nHD, b2 = b1 + nHD, b3 = b2 + nHD;
  constexpr size_t total = b3 + (size_t)cH * cD;
  const size_t i = ((size_t)blockIdx.x * 256 + threadIdx.x) * 4;
  if (i >= total) return;
  const float* s; unsigned short* d; size_t off;
  if (i < b0)      { s = s0; d = d0; off = i; }
  else if (i < b1) { s = s1; d = d1; off = i - b0; }
  else if (i < b2) { s = s2; d = d2; off = i - b1; }
  else if (i < b3) { s = s3; d = d3; off = i - b2; }
  else             { s = s4; d = d4; off = i - b3; }
  F4 v; v.v = *(const float4*)&s[off];
  *(ushort4*)&d[off] = make_ushort4(f2bf(v.a[0]), f2bf(v.a[1]),
                                    f2bf(v.a[2]), f2bf(v.a[3]));
}

// ------- interleave convert: dst rows (2r, 2r+1) = bf16(wz row r, wh row r) -
__global__ __launch_bounds__(256) void cvti2_k(const float* __restrict__ wz,
    const float* __restrict__ wh, unsigned short* __restrict__ d) {
  const size_t i = ((size_t)blockIdx.x * 256 + threadIdx.x) * 4;
  const int l = (int)(i >> 21);
  const int r = (int)((i >> 10) & (cH - 1));
  const int c = (int)(i & (cD - 1));
  F4 a, b; a.v = *(const float4*)&wz[i]; b.v = *(const float4*)&wh[i];
  const size_t dz = (((size_t)l * 2 * cH) + 2 * r) * cD + c;
  *(ushort4*)&d[dz] = make_ushort4(f2bf(a.a[0]), f2bf(a.a[1]),
                                   f2bf(a.a[2]), f2bf(a.a[3]));
  *(ushort4*)&d[dz + cD] = make_ushort4(f2bf(b.a[0]), f2bf(b.a[1]),
                                        f2bf(b.a[2]), f2bf(b.a[3]));
}

// ------- bias interleave: dst[l][2h]=bz, dst[l][2h+1]=bh (f32) -------------
__global__ __launch_bounds__(256) void biasi2_k(const float* __restrict__ bz,
    const float* __restrict__ bh, float* __restrict__ d) {
  const int i = blockIdx.x * 256 + threadIdx.x;   // cL*cH
  const int l = i >> 11, h = i & (cH - 1);
  d[((size_t)l * 2 * cH) + 2 * h]     = bz[i];
  d[((size_t)l * 2 * cH) + 2 * h + 1] = bh[i];
}

// shared phase sync/end for the 8-phase kernels
#define PH_SYNC()                                                           \
  __builtin_amdgcn_s_barrier();                                             \
  asm volatile("s_waitcnt lgkmcnt(0)" ::: "memory");                        \
  __builtin_amdgcn_sched_barrier(0);                                        \
  __builtin_amdgcn_s_setprio(1)

#define PH_END()                                                            \
  __builtin_amdgcn_s_setprio(0);                                            \
  __builtin_amdgcn_s_barrier()

// ======== 256x128 8-phase GEMM for the N=1024 trio (full occupancy) ========
// C[M,N] = A[M,K]*W[N,K]^T + bias, residual RMW (+=) into f32 Cf.
// BM=256, BN=128 -> grid (M/256, N/128) = 256 blocks = 1/CU exactly.
// Ledger: reads 10/2/8/0; stages ph1:A(T+1,h1)->OBUF, ph3:B(T+2)->BUF,
// ph4:A(T+2,h0)->BUF; steady vmcnt(4); peeled tail vmcnt(0).
#define RDA_N(BUF, MH)                                                      \
  _Pragma("unroll") for (int mf = 0; mf < 4; ++mf)                          \
  _Pragma("unroll") for (int kk = 0; kk < 2; ++kk)                          \
      a[mf * 2 + kk] = *(const bf16x8*)&lds[(BUF)*16384 + aB + (MH)*4096 +  \
                                            mf * 1024 + ((kk) ? ck1 : ck0)];

#define RDB_N(BUF, NH)                                                      \
  _Pragma("unroll") for (int kk = 0; kk < 2; ++kk)                          \
      b[NH][kk] = *(const bf16x8*)&lds[32768 + (BUF)*8192 + bB +            \
                                       (NH)*1024 + ((kk) ? ck1 : ck0)];

#define MMQ_N(MH, NH)                                                       \
  _Pragma("unroll") for (int mf = 0; mf < 4; ++mf)                          \
  _Pragma("unroll") for (int kk = 0; kk < 2; ++kk)                          \
      acc[(MH)*4 + mf][NH] = __builtin_amdgcn_mfma_f32_16x16x32_bf16(       \
          a[mf * 2 + kk], b[NH][kk], acc[(MH)*4 + mf][NH], 0, 0, 0);

#define TILE_N(TI, BUF, OBUF, S1, S2, VM)                                   \
  {                                                                         \
    RDA_N(BUF, 0); RDB_N(BUF, 0);                                           \
    if (S1) { stA((TI) + 1, 1, ldsA(OBUF, 1)); }                            \
    PH_SYNC(); MMQ_N(0, 0); PH_END();                                       \
    RDB_N(BUF, 1);                                                          \
    PH_SYNC(); MMQ_N(0, 1); PH_END();                                       \
    RDA_N(BUF, 1);                                                          \
    if (S2) { stB((TI) + 2, ldsB(BUF)); }                                   \
    PH_SYNC(); MMQ_N(1, 1); PH_END();                                       \
    if (S2) { stA((TI) + 2, 0, ldsA(BUF, 0)); }                             \
    if (VM == 4) { asm volatile("s_waitcnt vmcnt(4)" ::: "memory"); }       \
    else         { asm volatile("s_waitcnt vmcnt(0)" ::: "memory"); }       \
    PH_SYNC(); MMQ_N(1, 0); PH_END();                                       \
  }

template<int N, int K>
__global__ __launch_bounds__(512, 2) void gemm8n(
    const unsigned short* __restrict__ A,
    const unsigned short* __restrict__ W,
    const float* __restrict__ bias, float* __restrict__ Cf) {
  static_assert(K % 128 == 0, "NT must be even");
  constexpr int NT = K / 64;
  // LDS (ushort): A[buf] at buf*16384 (256x64 each); B[buf] at 32768+buf*8192
  // (128x64 each). 96 KiB total -> 1 block/CU, 8 waves.
  __shared__ unsigned short lds[49152];
  const int t = threadIdx.x;
  const int lane = t & 63;
  const int wave = t >> 6;
  const int wr = wave >> 2;   // M half (128 rows)
  const int wc = wave & 3;    // N quarter (32 cols)
  const int m0 = blockIdx.x * 256;
  const int n0 = blockIdx.y * 128;

  const int srow = t >> 3;
  const int scol = (((t & 7) ^ ((t >> 3) & 7)) * 8);   // 3-bit T2 key
  const unsigned short* gA = A + (size_t)(m0 + srow) * K + scol;
  const unsigned short* gB = W + (size_t)(n0 + srow) * K + scol;
  const int ldsw = wave * 512;

  auto ldsA = [&](int buf, int h) -> unsigned short* {
    return (unsigned short*)&lds[buf * 16384 + h * 8192 + ldsw];
  };
  auto ldsB = [&](int buf) -> unsigned short* {
    return (unsigned short*)&lds[32768 + buf * 8192 + ldsw];
  };
  auto stA = [&](int tile, int h, unsigned short* dst) {
    const unsigned short* s = gA + (size_t)(h * 128) * K + tile * 64;
    gld16(s, dst);
    gld16(s + (size_t)64 * K, dst + 4096);
  };
  auto stB = [&](int tile, unsigned short* dst) {
    const unsigned short* s = gB + (size_t)tile * 64;
    gld16(s, dst);
    gld16(s + (size_t)64 * K, dst + 4096);
  };

  const int swz = (lane & 7) << 3;
  const int ck0 = ((lane >> 4) * 8) ^ swz;
  const int ck1 = (32 + (lane >> 4) * 8) ^ swz;
  const int aB = wr * 8192 + (lane & 15) * 64;
  const int bB = wc * 2048 + (lane & 15) * 64;

  bf16x8 a[8];
  bf16x8 b[2][2];
  f32x4 acc[8][2] = {};

  // prologue: A0 full + B0 complete; {A1h0, B1} left in flight (A1h1 at ph1)
  stA(0, 0, ldsA(0, 0)); stA(0, 1, ldsA(0, 1));
  stB(0, ldsB(0));
  stA(1, 0, ldsA(1, 0));
  stB(1, ldsB(1));
  asm volatile("s_waitcnt vmcnt(4)" ::: "memory");
  __builtin_amdgcn_s_barrier();

  for (int tp = 0; tp < NT / 2 - 1; ++tp) {
    const int t0 = 2 * tp;
    TILE_N(t0, 0, 1, 1, 1, 4);
    TILE_N(t0 + 1, 1, 0, 1, 1, 4);
  }
  TILE_N(NT - 2, 0, 1, 1, 0, 0);
  TILE_N(NT - 1, 1, 0, 0, 0, 0);

  // epilogue: f32 residual RMW (64B-contiguous per 16 lanes)
  const int r0 = m0 + wr * 128 + ((lane >> 4) << 2);
  const int c0 = n0 + wc * 32 + (lane & 15);
#pragma unroll
  for (int mfg = 0; mfg < 8; ++mfg)
#pragma unroll
    for (int nfg = 0; nfg < 2; ++nfg) {
      const int col = c0 + nfg * 16;
      const float bv = bias[col];
#pragma unroll
      for (int r = 0; r < 4; ++r)
        Cf[(size_t)(r0 + mfg * 16 + r) * N + col] += acc[mfg][nfg][r] + bv;
    }
}

// ============ 256x256 8-phase GEMM (T2 3-bit swizzle + T3/T4 + T5) =========
#define RDA(BUF, MH)                                                        \
  _Pragma("unroll") for (int mf = 0; mf < 4; ++mf)                          \
  _Pragma("unroll") for (int kk = 0; kk < 2; ++kk)                          \
      a[mf * 2 + kk] = *(const bf16x8*)&lds[(BUF)*16384 + aB + (MH)*4096 +  \
                                            mf * 1024 + ((kk) ? ck1 : ck0)];

#define RDB0(BUF)                                                           \
  _Pragma("unroll") for (int q = 0; q < 2; ++q)                             \
  _Pragma("unroll") for (int kk = 0; kk < 2; ++kk)                          \
      b[0][q * 2 + kk] = *(const bf16x8*)&lds[(BUF)*16384 + bB + q * 1024 + \
                                              ((kk) ? ck1 : ck0)];

#define RDB1(BUF)                                                           \
  _Pragma("unroll") for (int q = 2; q < 4; ++q)                             \
  _Pragma("unroll") for (int kk = 0; kk < 2; ++kk)                          \
      b[1][(q & 1) * 2 + kk] =                                              \
          *(const bf16x8*)&lds[(BUF)*16384 + bB + q * 1024 +                \
                               ((kk) ? ck1 : ck0)];

#define MMQ(MH, NH)                                                         \
  _Pragma("unroll") for (int mf = 0; mf < 4; ++mf)                          \
  _Pragma("unroll") for (int nf = 0; nf < 2; ++nf)                          \
  _Pragma("unroll") for (int kk = 0; kk < 2; ++kk)                          \
      acc[(MH)*4 + mf][(NH)*2 + nf] = __builtin_amdgcn_mfma_f32_16x16x32_bf16( \
          a[mf * 2 + kk], b[NH][nf * 2 + kk], acc[(MH)*4 + mf][(NH)*2 + nf],  \
          0, 0, 0);

#define TILE_PHASES(TI, BUF, OBUF, S1, S2, VM)                              \
  {                                                                         \
    RDA(BUF, 0); RDB0(BUF);                                                 \
    if (S1) { stA((TI) + 1, 1, ldsA(OBUF, 1)); }                            \
    asm volatile("s_waitcnt lgkmcnt(8)" ::: "memory");                      \
    PH_SYNC(); MMQ(0, 0); PH_END();                                         \
    RDB1(BUF);                                                              \
    PH_SYNC(); MMQ(0, 1); PH_END();                                         \
    RDA(BUF, 1);                                                            \
    if (S2) { stB((TI) + 2, 0, ldsB(BUF, 0)); }                             \
    PH_SYNC(); MMQ(1, 1); PH_END();                                         \
    if (S2) { stB((TI) + 2, 1, ldsB(BUF, 1)); stA((TI) + 2, 0, ldsA(BUF, 0)); } \
    if (VM == 6) { asm volatile("s_waitcnt vmcnt(6)" ::: "memory"); }       \
    else         { asm volatile("s_waitcnt vmcnt(0)" ::: "memory"); }       \
    PH_SYNC(); MMQ(1, 0); PH_END();                                         \
  }

// EPI: 0 = f32 direct; 4 = gelu->bf16 (LDS-coalesced); 6 = interleaved
// z|htil + de-interleaved bf16 stores + FUSED scan1 -> Ac/Bc.
template<int N, int K, int EPI>
__global__ __launch_bounds__(512, 2) void gemm8p(
    const unsigned short* __restrict__ A,
    const unsigned short* __restrict__ W0,
    const float* __restrict__ bias0,
    float* __restrict__ Cf, unsigned short* __restrict__ Cb,
    unsigned short* __restrict__ Cb2,
    float* __restrict__ Ac, float* __restrict__ Bc) {
  static_assert(K % 128 == 0, "NT must be even");
  constexpr int NT = K / 64;
  __shared__ unsigned short lds[65536];   // 128 KiB; reused as [256][256]
  const int t = threadIdx.x;
  const int lane = t & 63;
  const int wave = t >> 6;
  const int wr = wave >> 2;
  const int wc = wave & 3;
  const int m0 = blockIdx.x * 256;
  const int n0 = blockIdx.y * 256;

  // --- staging addressing (pre-swizzled global source; linear LDS dest) ---
  const int srow = t >> 3;
  const int scol = (((t & 7) ^ ((t >> 3) & 7)) * 8);   // 3-bit T2 key
  const unsigned short* gA = A  + (size_t)(m0 + srow) * K + scol;
  const unsigned short* gB = W0 + (size_t)(n0 + srow) * K + scol;
  const int ldsw = wave * 512;

  auto ldsA = [&](int buf, int h) -> unsigned short* {
    return (unsigned short*)&lds[buf * 16384 + h * 8192 + ldsw];
  };
  auto ldsB = [&](int buf, int h) -> unsigned short* {
    return (unsigned short*)&lds[32768 + buf * 16384 + h * 8192 + ldsw];
  };
  auto stA = [&](int tile, int h, unsigned short* dst) {
    const unsigned short* s = gA + (size_t)(h * 128) * K + tile * 64;
    gld16(s, dst);
    gld16(s + (size_t)64 * K, dst + 4096);
  };
  auto stB = [&](int tile, int h, unsigned short* dst) {
    const unsigned short* s = gB + (size_t)(h * 128) * K + tile * 64;
    gld16(s, dst);
    gld16(s + (size_t)64 * K, dst + 4096);
  };

  // --- fragment read addressing (swizzled ds_read, 3-bit key = lane&7) ---
  const int swz = (lane & 7) << 3;
  const int ck0 = (((lane >> 4) * 8)) ^ swz;
  const int ck1 = (32 + ((lane >> 4) * 8)) ^ swz;
  const int aB = wr * 8192 + (lane & 15) * 64;
  const int bB = 32768 + (wc >> 1) * 8192 + (wc & 1) * 4096 + (lane & 15) * 64;

  bf16x8 a[8];
  bf16x8 b[2][4];
  f32x4 acc[8][4] = {};

  // --- prologue: A0,B0 full + {A1h0, B1h0, B1h1} left in flight ---
  stA(0, 0, ldsA(0, 0)); stA(0, 1, ldsA(0, 1));
  stB(0, 0, ldsB(0, 0)); stB(0, 1, ldsB(0, 1));
  stA(1, 0, ldsA(1, 0));
  stB(1, 0, ldsB(1, 0)); stB(1, 1, ldsB(1, 1));
  asm volatile("s_waitcnt vmcnt(6)" ::: "memory");
  __builtin_amdgcn_s_barrier();

  for (int tp = 0; tp < NT / 2 - 1; ++tp) {
    const int t0 = 2 * tp;
    TILE_PHASES(t0, 0, 1, 1, 1, 6);
    TILE_PHASES(t0 + 1, 1, 0, 1, 1, 6);
  }
  TILE_PHASES(NT - 2, 0, 1, 1, 0, 0);
  TILE_PHASES(NT - 1, 1, 0, 0, 0, 0);

  // --- epilogue ---
  const int r0l = wr * 128 + ((lane >> 4) << 2);
  const int c0l = wc * 64 + (lane & 15);
  if constexpr (EPI == 0) {
    const int r0 = m0 + r0l;
    const int c0 = n0 + c0l;
#pragma unroll
    for (int mfg = 0; mfg < 8; ++mfg)
#pragma unroll
      for (int nfg = 0; nfg < 4; ++nfg) {
        const int col = c0 + nfg * 16;
        const float bv = bias0[col];
#pragma unroll
        for (int r = 0; r < 4; ++r)
          Cf[(size_t)(r0 + mfg * 16 + r) * N + col] = acc[mfg][nfg][r] + bv;
      }
  } else {
    // activation -> swizzled LDS [256][256] -> coalesced stores
    const bool isz = ((lane & 1) == 0);   // EPI==6: even global col = z
#pragma unroll
    for (int mfg = 0; mfg < 8; ++mfg)
#pragma unroll
      for (int nfg = 0; nfg < 4; ++nfg) {
        const int col = c0l + nfg * 16;
        const float bv = bias0[n0 + col];
#pragma unroll
        for (int r = 0; r < 4; ++r) {
          const float v = acc[mfg][nfg][r] + bv;
          unsigned short o;
          if constexpr (EPI == 4) {
            o = f2bf(0.5f * v * (1.f + erff(v * 0.70710678118654752f)));
          } else {  // EPI == 6
            o = isz ? f2bf(1.f / (1.f + __expf(-v))) : f2bf(v);
          }
          const int rr = r0l + mfg * 16 + r;
          lds[rr * 256 + (col ^ (((rr >> 2) & 3) << 4))] = o;
        }
      }
    __syncthreads();
    if constexpr (EPI == 4) {
#pragma unroll
      for (int it = 0; it < 16; ++it) {
        const int flat = it * 512 + t;
        const int row = flat >> 5;
        const int ch = flat & 31;
        const float4 v = *(const float4*)&lds[row * 256 +
                                              ((ch * 8) ^ (((row >> 2) & 3) << 4))];
        *(float4*)&Cb[(size_t)(m0 + row) * N + n0 + ch * 8] = v;
      }
    } else {  // EPI == 6: de-interleave to Cb (z) / Cb2 (htil), width N/2
#pragma unroll
      for (int it = 0; it < 16; ++it) {
        const int flat = it * 512 + t;
        const int row = flat >> 5;
        const int ch = flat & 31;
        union { float4 v; unsigned u[4]; } q;
        q.v = *(const float4*)&lds[row * 256 +
                                   ((ch * 8) ^ (((row >> 2) & 3) << 4))];
        const ushort4 zz = make_ushort4(q.u[0] & 0xffff, q.u[1] & 0xffff,
                                        q.u[2] & 0xffff, q.u[3] & 0xffff);
        const ushort4 hh = make_ushort4(q.u[0] >> 16, q.u[1] >> 16,
                                        q.u[2] >> 16, q.u[3] >> 16);
        const size_t o = (size_t)(m0 + row) * (N / 2) + (n0 >> 1) + ch * 4;
        *(ushort4*)&Cb[o]  = zz;
        *(ushort4*)&Cb2[o] = hh;
      }
      // fused scan1: compose chunk-local (A,B) from the LDS bounce.
      if (t < 256) {
        const int lc = t >> 7;          // chunk half within tile
        const int lh = t & 127;         // local h
        float av = 1.f, bv = 0.f;
        const int s0 = lc * 128;
#pragma unroll 4
        for (int s = 0; s < CHS; ++s) {
          const int sr = s0 + s;
          const int c = (2 * lh) ^ (((sr >> 2) & 3) << 4);
          const unsigned w2 = *(const unsigned*)&lds[sr * 256 + c];
          const float zv = bf2f((unsigned short)(w2 & 0xffff));
          const float hv = bf2f((unsigned short)(w2 >> 16));
          const float aa = 1.f - zv;
          bv = aa * bv + zv * hv;
          av *= aa;
        }
        const int bidx = m0 / cS;
        const int ck = ((m0 & (cS - 1)) >> 7) + lc;
        const int hg = (n0 >> 1) + lh;
        const size_t so = ((size_t)bidx * NCH + ck) * cH + hg;
        Ac[so] = av;
        Bc[so] = bv;
      }
    }
  }
}

// fused scan2+scan3: per-thread prefix from chunk summaries, then replay;
// ck == NCH-1 threads emit h_next. (vectorized: 4 bf16 / 8B per lane)
__global__ __launch_bounds__(256) void scan23_k(const unsigned short* __restrict__ z,
    unsigned short* __restrict__ ht, const float* __restrict__ Ac,
    const float* __restrict__ Bc, const float* __restrict__ h_prev,
    float* __restrict__ hn, int l) {
  const int tid = blockIdx.x * 256 + threadIdx.x;
  const int hq = (tid & (cH / 4 - 1)) * 4;
  const int ck = (tid / (cH / 4)) & (NCH - 1);
  const int b = tid / ((cH / 4) * NCH);
  const size_t hoff = ((size_t)b * cL + l) * cH + hq;
  F4 h0; h0.v = *(const float4*)&h_prev[hoff];
  float r[4] = {h0.a[0], h0.a[1], h0.a[2], h0.a[3]};
  for (int c = 0; c < ck; ++c) {           // block-uniform trip count
    const size_t so = ((size_t)b * NCH + c) * cH + hq;
    F4 av, bv;
    av.v = *(const float4*)&Ac[so];
    bv.v = *(const float4*)&Bc[so];
#pragma unroll
    for (int j = 0; j < 4; ++j) r[j] = av.a[j] * r[j] + bv.a[j];
  }
  const size_t base = ((size_t)b * cS + (size_t)ck * CHS) * cH + hq;
#pragma unroll 4
  for (int s = 0; s < CHS; ++s) {
    const ushort4 zz = *(const ushort4*)&z[base + (size_t)s * cH];
    const ushort4 hh = *(const ushort4*)&ht[base + (size_t)s * cH];
    const float zf[4] = {bf2f(zz.x), bf2f(zz.y), bf2f(zz.z), bf2f(zz.w)};
    const float hf[4] = {bf2f(hh.x), bf2f(hh.y), bf2f(hh.z), bf2f(hh.w)};
#pragma unroll
    for (int j = 0; j < 4; ++j) r[j] = (1.f - zf[j]) * r[j] + zf[j] * hf[j];
    *(ushort4*)&ht[base + (size_t)s * cH] =
        make_ushort4(f2bf(r[0]), f2bf(r[1]), f2bf(r[2]), f2bf(r[3]));
  }
  if (ck == NCH - 1)
    *(float4*)&hn[hoff] = make_float4(r[0], r[1], r[2], r[3]);
}

extern "C" void kernel_launch(void* const* d_in, const int* in_sizes, int n_in,
                              void* d_out, int out_size, void* d_ws, size_t ws_size,
                              hipStream_t stream) {
  (void)in_sizes; (void)n_in; (void)out_size; (void)ws_size;
  const int*   x      = (const int*)d_in[0];
  const float* h_prev = (const float*)d_in[1];
  const float* emb    = (const float*)d_in[2];
  const float* cdw_w  = (const float*)d_in[3];
  const float* cdw_b  = (const float*)d_in[4];
  const float* cpw_w  = (const float*)d_in[5];
  const float* cpw_b  = (const float*)d_in[6];
  const float* n1w    = (const float*)d_in[7];
  const float* wzp    = (const float*)d_in[8];
  const float* bzp    = (const float*)d_in[9];
  const float* whp    = (const float*)d_in[10];
  const float* bhp    = (const float*)d_in[11];
  const float* wop    = (const float*)d_in[12];
  const float* bop    = (const float*)d_in[13];
  const float* n2w    = (const float*)d_in[14];
  const float* f1wp   = (const float*)d_in[15];
  const float* f1bp   = (const float*)d_in[16];
  const float* f2wp   = (const float*)d_in[17];
  const float* f2bp   = (const float*)d_in[18];
  const float* nw     = (const float*)d_in[19];
  const float* owp    = (const float*)d_in[20];
  const float* obp    = (const float*)d_in[21];

  float* out_main = (float*)d_out;                  // (B,S,H) f32
  float* out_hn   = out_main + (size_t)cM * cH;     // (B,L,H) f32

  char* p = (char*)d_ws;
  auto alloc = [&](size_t bytes) {
    char* r = p; p += (bytes + 255) & ~(size_t)255; return r;
  };
  float*          xe = (float*)alloc((size_t)cM * cD * 4);
  unsigned short* xn = (unsigned short*)alloc((size_t)cM * cD * 2);
  unsigned short* zb = (unsigned short*)alloc((size_t)cM * cH * 2);
  unsigned short* hb = (unsigned short*)alloc((size_t)cM * cH * 2);
  float* Ac = (float*)alloc((size_t)cB * NCH * cH * 4);
  float* Bc = (float*)alloc((size_t)cB * NCH * cH * 4);
  // all-layer bf16 weights (hoisted conversion)
  unsigned short* w_pw = (unsigned short*)alloc((size_t)cL * cD * cD * 2);
  unsigned short* w_zh = (unsigned short*)alloc((size_t)cL * 2 * cH * cD * 2);
  float*          bzh  = (float*)alloc((size_t)cL * 2 * cH * 4);
  unsigned short* w_o  = (unsigned short*)alloc((size_t)cL * cD * cH * 2);
  unsigned short* w_f1 = (unsigned short*)alloc((size_t)cL * cH * cD * 2);
  unsigned short* w_f2 = (unsigned short*)alloc((size_t)cL * cD * cH * 2);
  unsigned short* w_ow = (unsigned short*)alloc((size_t)cH * cD * 2);

  // merged weight prep: 3 dispatches total
  {
    constexpr size_t total = (size_t)cL * cD * cD + 3 * (size_t)cL * cD * cH +
                             (size_t)cH * cD;
    wcvt_k<<<dim3((unsigned)(total / 1024)), 256, 0, stream>>>(
        cpw_w, w_pw, wop, w_o, f1wp, w_f1, f2wp, w_f2, owp, w_ow);
    cvti2_k<<<dim3(cL * cH * cD / 1024), 256, 0, stream>>>(wzp, whp, w_zh);
    biasi2_k<<<dim3(cL * cH / 256), 256, 0, stream>>>(bzp, bhp, bzh);
  }

  embed_k<<<cM, 256, 0, stream>>>(x, emb, xe);

  for (int l = 0; l < cL; ++l) {
    const size_t oDD = (size_t)l * cD * cD, oHD = (size_t)l * cH * cD;

    // conv block: xe += pw(dwconv(xe)) + b
    dwconv_k<<<cM, 256, 0, stream>>>(xe, cdw_w + (size_t)l * cD * 3,
                                     cdw_b + (size_t)l * cD, xn);
    gemm8n<cD, cD><<<dim3(cM / 256, cD / 128), 512, 0, stream>>>(
        xn, w_pw + oDD, cpw_b + (size_t)l * cD, xe);

    // minGRU block: interleaved z|htil GEMM with fused scan1
    rmsnorm_k<<<cM, 256, 0, stream>>>(xe, n1w + (size_t)l * cD, xn);
    gemm8p<2 * cH, cD, 6><<<dim3(cM / 256, 2 * cH / 256), 512, 0, stream>>>(
        xn, w_zh + (size_t)l * 2 * cH * cD, bzh + (size_t)l * 2 * cH,
        nullptr, zb, hb, Ac, Bc);
    scan23_k<<<cB * NCH * (cH / 4) / 256, 256, 0, stream>>>(zb, hb, Ac, Bc,
                                                            h_prev, out_hn, l);
    gemm8n<cD, cH><<<dim3(cM / 256, cD / 128), 512, 0, stream>>>(
        hb, w_o + oHD, bop + (size_t)l * cD, xe);

    // FFN block
    rmsnorm_k<<<cM, 256, 0, stream>>>(xe, n2w + (size_t)l * cD, xn);
    gemm8p<cH, cD, 4><<<dim3(cM / 256, cH / 256), 512, 0, stream>>>(
        xn, w_f1 + oHD, f1bp + (size_t)l * cH, nullptr, zb, nullptr,
        nullptr, nullptr);
    gemm8n<cD, cH><<<dim3(cM / 256, cD / 128), 512, 0, stream>>>(
        zb, w_f2 + oHD, f2bp + (size_t)l * cD, xe);
  }

  rmsnorm_k<<<cM, 256, 0, stream>>>(xe, nw, xn);
  gemm8p<cH, cD, 0><<<dim3(cM / 256, cH / 256), 512, 0, stream>>>(
      xn, w_ow, obp, out_main, nullptr, nullptr, nullptr, nullptr);
}

// Round 14
// 1994.202 us; speedup vs baseline: 1.0935x; 1.0016x over previous
//
#include <hip/hip_runtime.h>

typedef __bf16 bf16x8 __attribute__((ext_vector_type(8)));
typedef float f32x4 __attribute__((ext_vector_type(4)));

#define DEVI __device__ __forceinline__

namespace {
constexpr int cB = 4, cS = 2048, cD = 1024, cH = 2048, cL = 6;
constexpr int cM = cB * cS;                  // 8192 rows
constexpr float cEPS = 1.1920929e-07f;       // torch float32 eps
constexpr int NCH = 16, CHS = cS / NCH;      // scan chunks: 16 x 128
}

DEVI unsigned short f2bf(float f) {
  union { float f; unsigned u; } c; c.f = f;
  const unsigned u = c.u;
  return (unsigned short)((u + 0x7fffu + ((u >> 16) & 1u)) >> 16);  // RNE
}
DEVI float bf2f(unsigned short h) {
  union { unsigned u; float f; } c; c.u = ((unsigned)h) << 16;
  return c.f;
}

DEVI void gld16(const void* g, void* l) {
  __builtin_amdgcn_global_load_lds(
      (__attribute__((address_space(1))) void*)g,
      (__attribute__((address_space(3))) void*)l, 16, 0, 0);
}

union F4 { float4 v; float a[4]; };

// ---------------- embedding gather ----------------
__global__ __launch_bounds__(256) void embed_k(const int* __restrict__ x,
    const float* __restrict__ emb, float* __restrict__ xe) {
  const int bs = blockIdx.x;
  const int idx = x[bs];
  const int t = threadIdx.x;
  *(float4*)&xe[(size_t)bs * cD + t * 4] =
      *(const float4*)&emb[(size_t)idx * cD + t * 4];
}

// ------------- depthwise conv (K=3, SAME) + bias -> bf16 ----------
__global__ __launch_bounds__(256) void dwconv_k(const float* __restrict__ xe,
    const float* __restrict__ w, const float* __restrict__ bias,
    unsigned short* __restrict__ out) {
  const int bs = blockIdx.x;
  const int s = bs & (cS - 1);
  const int t = threadIdx.x;
  const int d = t * 4;
  const size_t base = (size_t)bs * cD + d;
  F4 x0, xm, xp, vb;
  x0.v = *(const float4*)&xe[base];
  xm.v = make_float4(0.f, 0.f, 0.f, 0.f);
  xp.v = make_float4(0.f, 0.f, 0.f, 0.f);
  if (s > 0) xm.v = *(const float4*)&xe[base - cD];
  if (s < cS - 1) xp.v = *(const float4*)&xe[base + cD];
  vb.v = *(const float4*)&bias[d];
  unsigned short o[4];
#pragma unroll
  for (int j = 0; j < 4; ++j) {
    const float w0 = w[(d + j) * 3 + 0];
    const float w1 = w[(d + j) * 3 + 1];
    const float w2 = w[(d + j) * 3 + 2];
    o[j] = f2bf(xm.a[j] * w0 + x0.a[j] * w1 + xp.a[j] * w2 + vb.a[j]);
  }
  *(ushort4*)&out[base] = make_ushort4(o[0], o[1], o[2], o[3]);
}

// ---------------- RMSNorm row (D=1024) -> bf16 ----------------
__global__ __launch_bounds__(256) void rmsnorm_k(const float* __restrict__ x,
    const float* __restrict__ w, unsigned short* __restrict__ o) {
  const int row = blockIdx.x;
  const int t = threadIdx.x;
  const size_t base = (size_t)row * cD + t * 4;
  F4 v; v.v = *(const float4*)&x[base];
  float ss = v.a[0]*v.a[0] + v.a[1]*v.a[1] + v.a[2]*v.a[2] + v.a[3]*v.a[3];
#pragma unroll
  for (int off = 32; off > 0; off >>= 1) ss += __shfl_down(ss, off, 64);
  __shared__ float red[4];
  if ((t & 63) == 0) red[t >> 6] = ss;
  __syncthreads();
  const float scale = rsqrtf((red[0]+red[1]+red[2]+red[3]) * (1.f/cD) + cEPS);
  F4 wv; wv.v = *(const float4*)&w[t * 4];
  *(ushort4*)&o[base] = make_ushort4(
      f2bf(v.a[0]*scale*wv.a[0]), f2bf(v.a[1]*scale*wv.a[1]),
      f2bf(v.a[2]*scale*wv.a[2]), f2bf(v.a[3]*scale*wv.a[3]));
}

// ------- merged weight convert: all 5 plain f32->bf16 tensors, one grid ----
__global__ __launch_bounds__(256) void wcvt_k(
    const float* __restrict__ s0, unsigned short* __restrict__ d0,   // pw
    const float* __restrict__ s1, unsigned short* __restrict__ d1,   // o
    const float* __restrict__ s2, unsigned short* __restrict__ d2,   // f1
    const float* __restrict__ s3, unsigned short* __restrict__ d3,   // f2
    const float* __restrict__ s4, unsigned short* __restrict__ d4) { // ow
  constexpr size_t nPW = (size_t)cL * cD * cD;
  constexpr size_t nHD = (size_t)cL * cD * cH;
  constexpr size_t b0 = nPW, b1 = b0 + nHD, b2 = b1 + nHD, b3 = b2 + nHD;
  constexpr size_t total = b3 + (size_t)cH * cD;
  const size_t i = ((size_t)blockIdx.x * 256 + threadIdx.x) * 4;
  if (i >= total) return;
  const float* s; unsigned short* d; size_t off;
  if (i < b0)      { s = s0; d = d0; off = i; }
  else if (i < b1) { s = s1; d = d1; off = i - b0; }
  else if (i < b2) { s = s2; d = d2; off = i - b1; }
  else if (i < b3) { s = s3; d = d3; off = i - b2; }
  else             { s = s4; d = d4; off = i - b3; }
  F4 v; v.v = *(const float4*)&s[off];
  *(ushort4*)&d[off] = make_ushort4(f2bf(v.a[0]), f2bf(v.a[1]),
                                    f2bf(v.a[2]), f2bf(v.a[3]));
}

// ------- interleave convert: dst rows (2r, 2r+1) = bf16(wz row r, wh row r) -
__global__ __launch_bounds__(256) void cvti2_k(const float* __restrict__ wz,
    const float* __restrict__ wh, unsigned short* __restrict__ d) {
  const size_t i = ((size_t)blockIdx.x * 256 + threadIdx.x) * 4;
  const int l = (int)(i >> 21);
  const int r = (int)((i >> 10) & (cH - 1));
  const int c = (int)(i & (cD - 1));
  F4 a, b; a.v = *(const float4*)&wz[i]; b.v = *(const float4*)&wh[i];
  const size_t dz = (((size_t)l * 2 * cH) + 2 * r) * cD + c;
  *(ushort4*)&d[dz] = make_ushort4(f2bf(a.a[0]), f2bf(a.a[1]),
                                   f2bf(a.a[2]), f2bf(a.a[3]));
  *(ushort4*)&d[dz + cD] = make_ushort4(f2bf(b.a[0]), f2bf(b.a[1]),
                                        f2bf(b.a[2]), f2bf(b.a[3]));
}

// ------- bias interleave: dst[l][2h]=bz, dst[l][2h+1]=bh (f32) -------------
__global__ __launch_bounds__(256) void biasi2_k(const float* __restrict__ bz,
    const float* __restrict__ bh, float* __restrict__ d) {
  const int i = blockIdx.x * 256 + threadIdx.x;   // cL*cH
  const int l = i >> 11, h = i & (cH - 1);
  d[((size_t)l * 2 * cH) + 2 * h]     = bz[i];
  d[((size_t)l * 2 * cH) + 2 * h + 1] = bh[i];
}

// shared phase sync/end for the 8-phase kernels
// R14: no explicit lgkmcnt(0)/sched_barrier — compiler inserts fine-grained
// counted lgkm waits per MFMA operand, overlapping LDS drain with MFMA issue.
// Counted vmcnt asm (with "memory") still fences read-hoisting across staging.
#define PH_SYNC()                                                           \
  __builtin_amdgcn_s_barrier();                                             \
  __builtin_amdgcn_s_setprio(1)

#define PH_END()                                                            \
  __builtin_amdgcn_s_setprio(0);                                            \
  __builtin_amdgcn_s_barrier()

// ======== 256x128 8-phase GEMM for the N=1024 trio (full occupancy) ========
// C[M,N] = A[M,K]*W[N,K]^T + bias, residual RMW (+=) into f32 Cf.
// BM=256, BN=128 -> grid (M/256, N/128) = 256 blocks = 1/CU exactly.
// Ledger: reads 10/2/8/0; stages ph1:A(T+1,h1)->OBUF, ph3:B(T+2)->BUF,
// ph4:A(T+2,h0)->BUF; steady vmcnt(4); peeled tail vmcnt(0).
#define RDA_N(BUF, MH)                                                      \
  _Pragma("unroll") for (int mf = 0; mf < 4; ++mf)                          \
  _Pragma("unroll") for (int kk = 0; kk < 2; ++kk)                          \
      a[mf * 2 + kk] = *(const bf16x8*)&lds[(BUF)*16384 + aB + (MH)*4096 +  \
                                            mf * 1024 + ((kk) ? ck1 : ck0)];

#define RDB_N(BUF, NH)                                                      \
  _Pragma("unroll") for (int kk = 0; kk < 2; ++kk)                          \
      b[NH][kk] = *(const bf16x8*)&lds[32768 + (BUF)*8192 + bB +            \
                                       (NH)*1024 + ((kk) ? ck1 : ck0)];

#define MMQ_N(MH, NH)                                                       \
  _Pragma("unroll") for (int mf = 0; mf < 4; ++mf)                          \
  _Pragma("unroll") for (int kk = 0; kk < 2; ++kk)                          \
      acc[(MH)*4 + mf][NH] = __builtin_amdgcn_mfma_f32_16x16x32_bf16(       \
          a[mf * 2 + kk], b[NH][kk], acc[(MH)*4 + mf][NH], 0, 0, 0);

#define TILE_N(TI, BUF, OBUF, S1, S2, VM)                                   \
  {                                                                         \
    RDA_N(BUF, 0); RDB_N(BUF, 0);                                           \
    if (S1) { stA((TI) + 1, 1, ldsA(OBUF, 1)); }                            \
    PH_SYNC(); MMQ_N(0, 0); PH_END();                                       \
    RDB_N(BUF, 1);                                                          \
    PH_SYNC(); MMQ_N(0, 1); PH_END();                                       \
    RDA_N(BUF, 1);                                                          \
    if (S2) { stB((TI) + 2, ldsB(BUF)); }                                   \
    PH_SYNC(); MMQ_N(1, 1); PH_END();                                       \
    if (S2) { stA((TI) + 2, 0, ldsA(BUF, 0)); }                             \
    if (VM == 4) { asm volatile("s_waitcnt vmcnt(4)" ::: "memory"); }       \
    else         { asm volatile("s_waitcnt vmcnt(0)" ::: "memory"); }       \
    PH_SYNC(); MMQ_N(1, 0); PH_END();                                       \
  }

template<int N, int K>
__global__ __launch_bounds__(512, 2) void gemm8n(
    const unsigned short* __restrict__ A,
    const unsigned short* __restrict__ W,
    const float* __restrict__ bias, float* __restrict__ Cf) {
  static_assert(K % 128 == 0, "NT must be even");
  constexpr int NT = K / 64;
  // LDS (ushort): A[buf] at buf*16384 (256x64 each); B[buf] at 32768+buf*8192
  // (128x64 each). 96 KiB total -> 1 block/CU, 8 waves.
  __shared__ unsigned short lds[49152];
  const int t = threadIdx.x;
  const int lane = t & 63;
  const int wave = t >> 6;
  const int wr = wave >> 2;   // M half (128 rows)
  const int wc = wave & 3;    // N quarter (32 cols)
  const int m0 = blockIdx.x * 256;
  const int n0 = blockIdx.y * 128;

  const int srow = t >> 3;
  const int scol = (((t & 7) ^ ((t >> 3) & 7)) * 8);   // 3-bit T2 key
  const unsigned short* gA = A + (size_t)(m0 + srow) * K + scol;
  const unsigned short* gB = W + (size_t)(n0 + srow) * K + scol;
  const int ldsw = wave * 512;

  auto ldsA = [&](int buf, int h) -> unsigned short* {
    return (unsigned short*)&lds[buf * 16384 + h * 8192 + ldsw];
  };
  auto ldsB = [&](int buf) -> unsigned short* {
    return (unsigned short*)&lds[32768 + buf * 8192 + ldsw];
  };
  auto stA = [&](int tile, int h, unsigned short* dst) {
    const unsigned short* s = gA + (size_t)(h * 128) * K + tile * 64;
    gld16(s, dst);
    gld16(s + (size_t)64 * K, dst + 4096);
  };
  auto stB = [&](int tile, unsigned short* dst) {
    const unsigned short* s = gB + (size_t)tile * 64;
    gld16(s, dst);
    gld16(s + (size_t)64 * K, dst + 4096);
  };

  const int swz = (lane & 7) << 3;
  const int ck0 = ((lane >> 4) * 8) ^ swz;
  const int ck1 = (32 + (lane >> 4) * 8) ^ swz;
  const int aB = wr * 8192 + (lane & 15) * 64;
  const int bB = wc * 2048 + (lane & 15) * 64;

  bf16x8 a[8];
  bf16x8 b[2][2];
  f32x4 acc[8][2] = {};

  // prologue: A0 full + B0 complete; {A1h0, B1} left in flight (A1h1 at ph1)
  stA(0, 0, ldsA(0, 0)); stA(0, 1, ldsA(0, 1));
  stB(0, ldsB(0));
  stA(1, 0, ldsA(1, 0));
  stB(1, ldsB(1));
  asm volatile("s_waitcnt vmcnt(4)" ::: "memory");
  __builtin_amdgcn_s_barrier();

  for (int tp = 0; tp < NT / 2 - 1; ++tp) {
    const int t0 = 2 * tp;
    TILE_N(t0, 0, 1, 1, 1, 4);
    TILE_N(t0 + 1, 1, 0, 1, 1, 4);
  }
  TILE_N(NT - 2, 0, 1, 1, 0, 0);
  TILE_N(NT - 1, 1, 0, 0, 0, 0);

  // epilogue: f32 residual RMW (64B-contiguous per 16 lanes)
  const int r0 = m0 + wr * 128 + ((lane >> 4) << 2);
  const int c0 = n0 + wc * 32 + (lane & 15);
#pragma unroll
  for (int mfg = 0; mfg < 8; ++mfg)
#pragma unroll
    for (int nfg = 0; nfg < 2; ++nfg) {
      const int col = c0 + nfg * 16;
      const float bv = bias[col];
#pragma unroll
      for (int r = 0; r < 4; ++r)
        Cf[(size_t)(r0 + mfg * 16 + r) * N + col] += acc[mfg][nfg][r] + bv;
    }
}

// ============ 256x256 8-phase GEMM (T2 3-bit swizzle + T3/T4 + T5) =========
#define RDA(BUF, MH)                                                        \
  _Pragma("unroll") for (int mf = 0; mf < 4; ++mf)                          \
  _Pragma("unroll") for (int kk = 0; kk < 2; ++kk)                          \
      a[mf * 2 + kk] = *(const bf16x8*)&lds[(BUF)*16384 + aB + (MH)*4096 +  \
                                            mf * 1024 + ((kk) ? ck1 : ck0)];

#define RDB0(BUF)                                                           \
  _Pragma("unroll") for (int q = 0; q < 2; ++q)                             \
  _Pragma("unroll") for (int kk = 0; kk < 2; ++kk)                          \
      b[0][q * 2 + kk] = *(const bf16x8*)&lds[(BUF)*16384 + bB + q * 1024 + \
                                              ((kk) ? ck1 : ck0)];

#define RDB1(BUF)                                                           \
  _Pragma("unroll") for (int q = 2; q < 4; ++q)                             \
  _Pragma("unroll") for (int kk = 0; kk < 2; ++kk)                          \
      b[1][(q & 1) * 2 + kk] =                                              \
          *(const bf16x8*)&lds[(BUF)*16384 + bB + q * 1024 +                \
                               ((kk) ? ck1 : ck0)];

#define MMQ(MH, NH)                                                         \
  _Pragma("unroll") for (int mf = 0; mf < 4; ++mf)                          \
  _Pragma("unroll") for (int nf = 0; nf < 2; ++nf)                          \
  _Pragma("unroll") for (int kk = 0; kk < 2; ++kk)                          \
      acc[(MH)*4 + mf][(NH)*2 + nf] = __builtin_amdgcn_mfma_f32_16x16x32_bf16( \
          a[mf * 2 + kk], b[NH][nf * 2 + kk], acc[(MH)*4 + mf][(NH)*2 + nf],  \
          0, 0, 0);

#define TILE_PHASES(TI, BUF, OBUF, S1, S2, VM)                              \
  {                                                                         \
    RDA(BUF, 0); RDB0(BUF);                                                 \
    if (S1) { stA((TI) + 1, 1, ldsA(OBUF, 1)); }                            \
    PH_SYNC(); MMQ(0, 0); PH_END();                                         \
    RDB1(BUF);                                                              \
    PH_SYNC(); MMQ(0, 1); PH_END();                                         \
    RDA(BUF, 1);                                                            \
    if (S2) { stB((TI) + 2, 0, ldsB(BUF, 0)); }                             \
    PH_SYNC(); MMQ(1, 1); PH_END();                                         \
    if (S2) { stB((TI) + 2, 1, ldsB(BUF, 1)); stA((TI) + 2, 0, ldsA(BUF, 0)); } \
    if (VM == 6) { asm volatile("s_waitcnt vmcnt(6)" ::: "memory"); }       \
    else         { asm volatile("s_waitcnt vmcnt(0)" ::: "memory"); }       \
    PH_SYNC(); MMQ(1, 0); PH_END();                                         \
  }

// EPI: 0 = f32 direct; 4 = gelu->bf16 (LDS-coalesced); 6 = interleaved
// z|htil + de-interleaved bf16 stores + FUSED scan1 -> Ac/Bc.
template<int N, int K, int EPI>
__global__ __launch_bounds__(512, 2) void gemm8p(
    const unsigned short* __restrict__ A,
    const unsigned short* __restrict__ W0,
    const float* __restrict__ bias0,
    float* __restrict__ Cf, unsigned short* __restrict__ Cb,
    unsigned short* __restrict__ Cb2,
    float* __restrict__ Ac, float* __restrict__ Bc) {
  static_assert(K % 128 == 0, "NT must be even");
  constexpr int NT = K / 64;
  __shared__ unsigned short lds[65536];   // 128 KiB; reused as [256][256]
  const int t = threadIdx.x;
  const int lane = t & 63;
  const int wave = t >> 6;
  const int wr = wave >> 2;
  const int wc = wave & 3;
  const int m0 = blockIdx.x * 256;
  const int n0 = blockIdx.y * 256;

  // --- staging addressing (pre-swizzled global source; linear LDS dest) ---
  const int srow = t >> 3;
  const int scol = (((t & 7) ^ ((t >> 3) & 7)) * 8);   // 3-bit T2 key
  const unsigned short* gA = A  + (size_t)(m0 + srow) * K + scol;
  const unsigned short* gB = W0 + (size_t)(n0 + srow) * K + scol;
  const int ldsw = wave * 512;

  auto ldsA = [&](int buf, int h) -> unsigned short* {
    return (unsigned short*)&lds[buf * 16384 + h * 8192 + ldsw];
  };
  auto ldsB = [&](int buf, int h) -> unsigned short* {
    return (unsigned short*)&lds[32768 + buf * 16384 + h * 8192 + ldsw];
  };
  auto stA = [&](int tile, int h, unsigned short* dst) {
    const unsigned short* s = gA + (size_t)(h * 128) * K + tile * 64;
    gld16(s, dst);
    gld16(s + (size_t)64 * K, dst + 4096);
  };
  auto stB = [&](int tile, int h, unsigned short* dst) {
    const unsigned short* s = gB + (size_t)(h * 128) * K + tile * 64;
    gld16(s, dst);
    gld16(s + (size_t)64 * K, dst + 4096);
  };

  // --- fragment read addressing (swizzled ds_read, 3-bit key = lane&7) ---
  const int swz = (lane & 7) << 3;
  const int ck0 = (((lane >> 4) * 8)) ^ swz;
  const int ck1 = (32 + ((lane >> 4) * 8)) ^ swz;
  const int aB = wr * 8192 + (lane & 15) * 64;
  const int bB = 32768 + (wc >> 1) * 8192 + (wc & 1) * 4096 + (lane & 15) * 64;

  bf16x8 a[8];
  bf16x8 b[2][4];
  f32x4 acc[8][4] = {};

  // --- prologue: A0,B0 full + {A1h0, B1h0, B1h1} left in flight ---
  stA(0, 0, ldsA(0, 0)); stA(0, 1, ldsA(0, 1));
  stB(0, 0, ldsB(0, 0)); stB(0, 1, ldsB(0, 1));
  stA(1, 0, ldsA(1, 0));
  stB(1, 0, ldsB(1, 0)); stB(1, 1, ldsB(1, 1));
  asm volatile("s_waitcnt vmcnt(6)" ::: "memory");
  __builtin_amdgcn_s_barrier();

  for (int tp = 0; tp < NT / 2 - 1; ++tp) {
    const int t0 = 2 * tp;
    TILE_PHASES(t0, 0, 1, 1, 1, 6);
    TILE_PHASES(t0 + 1, 1, 0, 1, 1, 6);
  }
  TILE_PHASES(NT - 2, 0, 1, 1, 0, 0);
  TILE_PHASES(NT - 1, 1, 0, 0, 0, 0);

  // --- epilogue ---
  const int r0l = wr * 128 + ((lane >> 4) << 2);
  const int c0l = wc * 64 + (lane & 15);
  if constexpr (EPI == 0) {
    const int r0 = m0 + r0l;
    const int c0 = n0 + c0l;
#pragma unroll
    for (int mfg = 0; mfg < 8; ++mfg)
#pragma unroll
      for (int nfg = 0; nfg < 4; ++nfg) {
        const int col = c0 + nfg * 16;
        const float bv = bias0[col];
#pragma unroll
        for (int r = 0; r < 4; ++r)
          Cf[(size_t)(r0 + mfg * 16 + r) * N + col] = acc[mfg][nfg][r] + bv;
      }
  } else {
    // activation -> swizzled LDS [256][256] -> coalesced stores
    const bool isz = ((lane & 1) == 0);   // EPI==6: even global col = z
#pragma unroll
    for (int mfg = 0; mfg < 8; ++mfg)
#pragma unroll
      for (int nfg = 0; nfg < 4; ++nfg) {
        const int col = c0l + nfg * 16;
        const float bv = bias0[n0 + col];
#pragma unroll
        for (int r = 0; r < 4; ++r) {
          const float v = acc[mfg][nfg][r] + bv;
          unsigned short o;
          if constexpr (EPI == 4) {
            o = f2bf(0.5f * v * (1.f + erff(v * 0.70710678118654752f)));
          } else {  // EPI == 6
            o = isz ? f2bf(1.f / (1.f + __expf(-v))) : f2bf(v);
          }
          const int rr = r0l + mfg * 16 + r;
          lds[rr * 256 + (col ^ (((rr >> 2) & 3) << 4))] = o;
        }
      }
    __syncthreads();
    if constexpr (EPI == 4) {
#pragma unroll
      for (int it = 0; it < 16; ++it) {
        const int flat = it * 512 + t;
        const int row = flat >> 5;
        const int ch = flat & 31;
        const float4 v = *(const float4*)&lds[row * 256 +
                                              ((ch * 8) ^ (((row >> 2) & 3) << 4))];
        *(float4*)&Cb[(size_t)(m0 + row) * N + n0 + ch * 8] = v;
      }
    } else {  // EPI == 6: de-interleave to Cb (z) / Cb2 (htil), width N/2
#pragma unroll
      for (int it = 0; it < 16; ++it) {
        const int flat = it * 512 + t;
        const int row = flat >> 5;
        const int ch = flat & 31;
        union { float4 v; unsigned u[4]; } q;
        q.v = *(const float4*)&lds[row * 256 +
                                   ((ch * 8) ^ (((row >> 2) & 3) << 4))];
        const ushort4 zz = make_ushort4(q.u[0] & 0xffff, q.u[1] & 0xffff,
                                        q.u[2] & 0xffff, q.u[3] & 0xffff);
        const ushort4 hh = make_ushort4(q.u[0] >> 16, q.u[1] >> 16,
                                        q.u[2] >> 16, q.u[3] >> 16);
        const size_t o = (size_t)(m0 + row) * (N / 2) + (n0 >> 1) + ch * 4;
        *(ushort4*)&Cb[o]  = zz;
        *(ushort4*)&Cb2[o] = hh;
      }
      // fused scan1: compose chunk-local (A,B) from the LDS bounce.
      if (t < 256) {
        const int lc = t >> 7;          // chunk half within tile
        const int lh = t & 127;         // local h
        float av = 1.f, bv = 0.f;
        const int s0 = lc * 128;
#pragma unroll 4
        for (int s = 0; s < CHS; ++s) {
          const int sr = s0 + s;
          const int c = (2 * lh) ^ (((sr >> 2) & 3) << 4);
          const unsigned w2 = *(const unsigned*)&lds[sr * 256 + c];
          const float zv = bf2f((unsigned short)(w2 & 0xffff));
          const float hv = bf2f((unsigned short)(w2 >> 16));
          const float aa = 1.f - zv;
          bv = aa * bv + zv * hv;
          av *= aa;
        }
        const int bidx = m0 / cS;
        const int ck = ((m0 & (cS - 1)) >> 7) + lc;
        const int hg = (n0 >> 1) + lh;
        const size_t so = ((size_t)bidx * NCH + ck) * cH + hg;
        Ac[so] = av;
        Bc[so] = bv;
      }
    }
  }
}

// fused scan2+scan3: per-thread prefix from chunk summaries, then replay;
// ck == NCH-1 threads emit h_next. (vectorized: 4 bf16 / 8B per lane)
__global__ __launch_bounds__(256) void scan23_k(const unsigned short* __restrict__ z,
    unsigned short* __restrict__ ht, const float* __restrict__ Ac,
    const float* __restrict__ Bc, const float* __restrict__ h_prev,
    float* __restrict__ hn, int l) {
  const int tid = blockIdx.x * 256 + threadIdx.x;
  const int hq = (tid & (cH / 4 - 1)) * 4;
  const int ck = (tid / (cH / 4)) & (NCH - 1);
  const int b = tid / ((cH / 4) * NCH);
  const size_t hoff = ((size_t)b * cL + l) * cH + hq;
  F4 h0; h0.v = *(const float4*)&h_prev[hoff];
  float r[4] = {h0.a[0], h0.a[1], h0.a[2], h0.a[3]};
  for (int c = 0; c < ck; ++c) {           // block-uniform trip count
    const size_t so = ((size_t)b * NCH + c) * cH + hq;
    F4 av, bv;
    av.v = *(const float4*)&Ac[so];
    bv.v = *(const float4*)&Bc[so];
#pragma unroll
    for (int j = 0; j < 4; ++j) r[j] = av.a[j] * r[j] + bv.a[j];
  }
  const size_t base = ((size_t)b * cS + (size_t)ck * CHS) * cH + hq;
#pragma unroll 4
  for (int s = 0; s < CHS; ++s) {
    const ushort4 zz = *(const ushort4*)&z[base + (size_t)s * cH];
    const ushort4 hh = *(const ushort4*)&ht[base + (size_t)s * cH];
    const float zf[4] = {bf2f(zz.x), bf2f(zz.y), bf2f(zz.z), bf2f(zz.w)};
    const float hf[4] = {bf2f(hh.x), bf2f(hh.y), bf2f(hh.z), bf2f(hh.w)};
#pragma unroll
    for (int j = 0; j < 4; ++j) r[j] = (1.f - zf[j]) * r[j] + zf[j] * hf[j];
    *(ushort4*)&ht[base + (size_t)s * cH] =
        make_ushort4(f2bf(r[0]), f2bf(r[1]), f2bf(r[2]), f2bf(r[3]));
  }
  if (ck == NCH - 1)
    *(float4*)&hn[hoff] = make_float4(r[0], r[1], r[2], r[3]);
}

extern "C" void kernel_launch(void* const* d_in, const int* in_sizes, int n_in,
                              void* d_out, int out_size, void* d_ws, size_t ws_size,
                              hipStream_t stream) {
  (void)in_sizes; (void)n_in; (void)out_size; (void)ws_size;
  const int*   x      = (const int*)d_in[0];
  const float* h_prev = (const float*)d_in[1];
  const float* emb    = (const float*)d_in[2];
  const float* cdw_w  = (const float*)d_in[3];
  const float* cdw_b  = (const float*)d_in[4];
  const float* cpw_w  = (const float*)d_in[5];
  const float* cpw_b  = (const float*)d_in[6];
  const float* n1w    = (const float*)d_in[7];
  const float* wzp    = (const float*)d_in[8];
  const float* bzp    = (const float*)d_in[9];
  const float* whp    = (const float*)d_in[10];
  const float* bhp    = (const float*)d_in[11];
  const float* wop    = (const float*)d_in[12];
  const float* bop    = (const float*)d_in[13];
  const float* n2w    = (const float*)d_in[14];
  const float* f1wp   = (const float*)d_in[15];
  const float* f1bp   = (const float*)d_in[16];
  const float* f2wp   = (const float*)d_in[17];
  const float* f2bp   = (const float*)d_in[18];
  const float* nw     = (const float*)d_in[19];
  const float* owp    = (const float*)d_in[20];
  const float* obp    = (const float*)d_in[21];

  float* out_main = (float*)d_out;                  // (B,S,H) f32
  float* out_hn   = out_main + (size_t)cM * cH;     // (B,L,H) f32

  char* p = (char*)d_ws;
  auto alloc = [&](size_t bytes) {
    char* r = p; p += (bytes + 255) & ~(size_t)255; return r;
  };
  float*          xe = (float*)alloc((size_t)cM * cD * 4);
  unsigned short* xn = (unsigned short*)alloc((size_t)cM * cD * 2);
  unsigned short* zb = (unsigned short*)alloc((size_t)cM * cH * 2);
  unsigned short* hb = (unsigned short*)alloc((size_t)cM * cH * 2);
  float* Ac = (float*)alloc((size_t)cB * NCH * cH * 4);
  float* Bc = (float*)alloc((size_t)cB * NCH * cH * 4);
  // all-layer bf16 weights (hoisted conversion)
  unsigned short* w_pw = (unsigned short*)alloc((size_t)cL * cD * cD * 2);
  unsigned short* w_zh = (unsigned short*)alloc((size_t)cL * 2 * cH * cD * 2);
  float*          bzh  = (float*)alloc((size_t)cL * 2 * cH * 4);
  unsigned short* w_o  = (unsigned short*)alloc((size_t)cL * cD * cH * 2);
  unsigned short* w_f1 = (unsigned short*)alloc((size_t)cL * cH * cD * 2);
  unsigned short* w_f2 = (unsigned short*)alloc((size_t)cL * cD * cH * 2);
  unsigned short* w_ow = (unsigned short*)alloc((size_t)cH * cD * 2);

  // merged weight prep: 3 dispatches total
  {
    constexpr size_t total = (size_t)cL * cD * cD + 3 * (size_t)cL * cD * cH +
                             (size_t)cH * cD;
    wcvt_k<<<dim3((unsigned)(total / 1024)), 256, 0, stream>>>(
        cpw_w, w_pw, wop, w_o, f1wp, w_f1, f2wp, w_f2, owp, w_ow);
    cvti2_k<<<dim3(cL * cH * cD / 1024), 256, 0, stream>>>(wzp, whp, w_zh);
    biasi2_k<<<dim3(cL * cH / 256), 256, 0, stream>>>(bzp, bhp, bzh);
  }

  embed_k<<<cM, 256, 0, stream>>>(x, emb, xe);

  for (int l = 0; l < cL; ++l) {
    const size_t oDD = (size_t)l * cD * cD, oHD = (size_t)l * cH * cD;

    // conv block: xe += pw(dwconv(xe)) + b
    dwconv_k<<<cM, 256, 0, stream>>>(xe, cdw_w + (size_t)l * cD * 3,
                                     cdw_b + (size_t)l * cD, xn);
    gemm8n<cD, cD><<<dim3(cM / 256, cD / 128), 512, 0, stream>>>(
        xn, w_pw + oDD, cpw_b + (size_t)l * cD, xe);

    // minGRU block: interleaved z|htil GEMM with fused scan1
    rmsnorm_k<<<cM, 256, 0, stream>>>(xe, n1w + (size_t)l * cD, xn);
    gemm8p<2 * cH, cD, 6><<<dim3(cM / 256, 2 * cH / 256), 512, 0, stream>>>(
        xn, w_zh + (size_t)l * 2 * cH * cD, bzh + (size_t)l * 2 * cH,
        nullptr, zb, hb, Ac, Bc);
    scan23_k<<<cB * NCH * (cH / 4) / 256, 256, 0, stream>>>(zb, hb, Ac, Bc,
                                                            h_prev, out_hn, l);
    gemm8n<cD, cH><<<dim3(cM / 256, cD / 128), 512, 0, stream>>>(
        hb, w_o + oHD, bop + (size_t)l * cD, xe);

    // FFN block
    rmsnorm_k<<<cM, 256, 0, stream>>>(xe, n2w + (size_t)l * cD, xn);
    gemm8p<cH, cD, 4><<<dim3(cM / 256, cH / 256), 512, 0, stream>>>(
        xn, w_f1 + oHD, f1bp + (size_t)l * cH, nullptr, zb, nullptr,
        nullptr, nullptr);
    gemm8n<cD, cH><<<dim3(cM / 256, cD / 128), 512, 0, stream>>>(
        zb, w_f2 + oHD, f2bp + (size_t)l * cD, xe);
  }

  rmsnorm_k<<<cM, 256, 0, stream>>>(xe, nw, xn);
  gemm8p<cH, cD, 0><<<dim3(cM / 256, cH / 128 / 2), 512, 0, stream>>>(
      xn, w_ow, obp, out_main, nullptr, nullptr, nullptr, nullptr);
}

// Round 15
// 1975.827 us; speedup vs baseline: 1.1037x; 1.0093x over previous
//
#include <hip/hip_runtime.h>

typedef __bf16 bf16x8 __attribute__((ext_vector_type(8)));
typedef float f32x4 __attribute__((ext_vector_type(4)));

#define DEVI __device__ __forceinline__

namespace {
constexpr int cB = 4, cS = 2048, cD = 1024, cH = 2048, cL = 6;
constexpr int cM = cB * cS;                  // 8192 rows
constexpr float cEPS = 1.1920929e-07f;       // torch float32 eps
constexpr int NCH = 16, CHS = cS / NCH;      // scan chunks: 16 x 128
}

DEVI unsigned short f2bf(float f) {
  union { float f; unsigned u; } c; c.f = f;
  const unsigned u = c.u;
  return (unsigned short)((u + 0x7fffu + ((u >> 16) & 1u)) >> 16);  // RNE
}
DEVI float bf2f(unsigned short h) {
  union { unsigned u; float f; } c; c.u = ((unsigned)h) << 16;
  return c.f;
}

DEVI void gld16(const void* g, void* l) {
  __builtin_amdgcn_global_load_lds(
      (__attribute__((address_space(1))) void*)g,
      (__attribute__((address_space(3))) void*)l, 16, 0, 0);
}

union F4 { float4 v; float a[4]; };

// ---------------- embedding gather ----------------
__global__ __launch_bounds__(256) void embed_k(const int* __restrict__ x,
    const float* __restrict__ emb, float* __restrict__ xe) {
  const int bs = blockIdx.x;
  const int idx = x[bs];
  const int t = threadIdx.x;
  *(float4*)&xe[(size_t)bs * cD + t * 4] =
      *(const float4*)&emb[(size_t)idx * cD + t * 4];
}

// ------------- depthwise conv (K=3, SAME) + bias -> bf16 ----------
__global__ __launch_bounds__(256) void dwconv_k(const float* __restrict__ xe,
    const float* __restrict__ w, const float* __restrict__ bias,
    unsigned short* __restrict__ out) {
  const int bs = blockIdx.x;
  const int s = bs & (cS - 1);
  const int t = threadIdx.x;
  const int d = t * 4;
  const size_t base = (size_t)bs * cD + d;
  F4 x0, xm, xp, vb;
  x0.v = *(const float4*)&xe[base];
  xm.v = make_float4(0.f, 0.f, 0.f, 0.f);
  xp.v = make_float4(0.f, 0.f, 0.f, 0.f);
  if (s > 0) xm.v = *(const float4*)&xe[base - cD];
  if (s < cS - 1) xp.v = *(const float4*)&xe[base + cD];
  vb.v = *(const float4*)&bias[d];
  unsigned short o[4];
#pragma unroll
  for (int j = 0; j < 4; ++j) {
    const float w0 = w[(d + j) * 3 + 0];
    const float w1 = w[(d + j) * 3 + 1];
    const float w2 = w[(d + j) * 3 + 2];
    o[j] = f2bf(xm.a[j] * w0 + x0.a[j] * w1 + xp.a[j] * w2 + vb.a[j]);
  }
  *(ushort4*)&out[base] = make_ushort4(o[0], o[1], o[2], o[3]);
}

// ---------------- RMSNorm row (D=1024) -> bf16 ----------------
__global__ __launch_bounds__(256) void rmsnorm_k(const float* __restrict__ x,
    const float* __restrict__ w, unsigned short* __restrict__ o) {
  const int row = blockIdx.x;
  const int t = threadIdx.x;
  const size_t base = (size_t)row * cD + t * 4;
  F4 v; v.v = *(const float4*)&x[base];
  float ss = v.a[0]*v.a[0] + v.a[1]*v.a[1] + v.a[2]*v.a[2] + v.a[3]*v.a[3];
#pragma unroll
  for (int off = 32; off > 0; off >>= 1) ss += __shfl_down(ss, off, 64);
  __shared__ float red[4];
  if ((t & 63) == 0) red[t >> 6] = ss;
  __syncthreads();
  const float scale = rsqrtf((red[0]+red[1]+red[2]+red[3]) * (1.f/cD) + cEPS);
  F4 wv; wv.v = *(const float4*)&w[t * 4];
  *(ushort4*)&o[base] = make_ushort4(
      f2bf(v.a[0]*scale*wv.a[0]), f2bf(v.a[1]*scale*wv.a[1]),
      f2bf(v.a[2]*scale*wv.a[2]), f2bf(v.a[3]*scale*wv.a[3]));
}

// ------- merged weight convert: all 5 plain f32->bf16 tensors, one grid ----
__global__ __launch_bounds__(256) void wcvt_k(
    const float* __restrict__ s0, unsigned short* __restrict__ d0,   // pw
    const float* __restrict__ s1, unsigned short* __restrict__ d1,   // o
    const float* __restrict__ s2, unsigned short* __restrict__ d2,   // f1
    const float* __restrict__ s3, unsigned short* __restrict__ d3,   // f2
    const float* __restrict__ s4, unsigned short* __restrict__ d4) { // ow
  constexpr size_t nPW = (size_t)cL * cD * cD;
  constexpr size_t nHD = (size_t)cL * cD * cH;
  constexpr size_t b0 = nPW, b1 = b0 + nHD, b2 = b1 + nHD, b3 = b2 + nHD;
  constexpr size_t total = b3 + (size_t)cH * cD;
  const size_t i = ((size_t)blockIdx.x * 256 + threadIdx.x) * 4;
  if (i >= total) return;
  const float* s; unsigned short* d; size_t off;
  if (i < b0)      { s = s0; d = d0; off = i; }
  else if (i < b1) { s = s1; d = d1; off = i - b0; }
  else if (i < b2) { s = s2; d = d2; off = i - b1; }
  else if (i < b3) { s = s3; d = d3; off = i - b2; }
  else             { s = s4; d = d4; off = i - b3; }
  F4 v; v.v = *(const float4*)&s[off];
  *(ushort4*)&d[off] = make_ushort4(f2bf(v.a[0]), f2bf(v.a[1]),
                                    f2bf(v.a[2]), f2bf(v.a[3]));
}

// ------- interleave convert: dst rows (2r, 2r+1) = bf16(wz row r, wh row r) -
__global__ __launch_bounds__(256) void cvti2_k(const float* __restrict__ wz,
    const float* __restrict__ wh, unsigned short* __restrict__ d) {
  const size_t i = ((size_t)blockIdx.x * 256 + threadIdx.x) * 4;
  const int l = (int)(i >> 21);
  const int r = (int)((i >> 10) & (cH - 1));
  const int c = (int)(i & (cD - 1));
  F4 a, b; a.v = *(const float4*)&wz[i]; b.v = *(const float4*)&wh[i];
  const size_t dz = (((size_t)l * 2 * cH) + 2 * r) * cD + c;
  *(ushort4*)&d[dz] = make_ushort4(f2bf(a.a[0]), f2bf(a.a[1]),
                                   f2bf(a.a[2]), f2bf(a.a[3]));
  *(ushort4*)&d[dz + cD] = make_ushort4(f2bf(b.a[0]), f2bf(b.a[1]),
                                        f2bf(b.a[2]), f2bf(b.a[3]));
}

// ------- bias interleave: dst[l][2h]=bz, dst[l][2h+1]=bh (f32) -------------
__global__ __launch_bounds__(256) void biasi2_k(const float* __restrict__ bz,
    const float* __restrict__ bh, float* __restrict__ d) {
  const int i = blockIdx.x * 256 + threadIdx.x;   // cL*cH
  const int l = i >> 11, h = i & (cH - 1);
  d[((size_t)l * 2 * cH) + 2 * h]     = bz[i];
  d[((size_t)l * 2 * cH) + 2 * h + 1] = bh[i];
}

// shared phase sync/end for the 8-phase kernels
// (R14-validated: no explicit lgkmcnt pin; compiler emits counted lgkm waits.)
#define PH_SYNC()                                                           \
  __builtin_amdgcn_s_barrier();                                             \
  __builtin_amdgcn_s_setprio(1)

#define PH_END()                                                            \
  __builtin_amdgcn_s_setprio(0);                                            \
  __builtin_amdgcn_s_barrier()

// ======== 256x128 8-phase GEMM for the N=1024 trio (full occupancy) ========
// C[M,N] = A[M,K]*W[N,K]^T + bias, residual RMW (+=) into f32 Cf.
// BM=256, BN=128 -> grid (M/256, N/128) = 256 blocks = 1/CU exactly.
// Ledger: stages ph1:A(T+1,h1)->OBUF, ph3:B(T+2)->BUF, ph4:A(T+2,h0)->BUF;
// steady vmcnt(4); peeled tail vmcnt(0).
#define RDA_N(BUF, MH)                                                      \
  _Pragma("unroll") for (int mf = 0; mf < 4; ++mf)                          \
  _Pragma("unroll") for (int kk = 0; kk < 2; ++kk)                          \
      a[mf * 2 + kk] = *(const bf16x8*)&lds[(BUF)*16384 + aB + (MH)*4096 +  \
                                            mf * 1024 + ((kk) ? ck1 : ck0)];

#define RDB_N(BUF, NH)                                                      \
  _Pragma("unroll") for (int kk = 0; kk < 2; ++kk)                          \
      b[NH][kk] = *(const bf16x8*)&lds[32768 + (BUF)*8192 + bB +            \
                                       (NH)*1024 + ((kk) ? ck1 : ck0)];

#define MMQ_N(MH, NH)                                                       \
  _Pragma("unroll") for (int mf = 0; mf < 4; ++mf)                          \
  _Pragma("unroll") for (int kk = 0; kk < 2; ++kk)                          \
      acc[(MH)*4 + mf][NH] = __builtin_amdgcn_mfma_f32_16x16x32_bf16(       \
          a[mf * 2 + kk], b[NH][kk], acc[(MH)*4 + mf][NH], 0, 0, 0);

#define TILE_N(TI, BUF, OBUF, S1, S2, VM)                                   \
  {                                                                         \
    RDA_N(BUF, 0); RDB_N(BUF, 0);                                           \
    if (S1) { stA((TI) + 1, 1, ldsA(OBUF, 1)); }                            \
    PH_SYNC(); MMQ_N(0, 0); PH_END();                                       \
    RDB_N(BUF, 1);                                                          \
    PH_SYNC(); MMQ_N(0, 1); PH_END();                                       \
    RDA_N(BUF, 1);                                                          \
    if (S2) { stB((TI) + 2, ldsB(BUF)); }                                   \
    PH_SYNC(); MMQ_N(1, 1); PH_END();                                       \
    if (S2) { stA((TI) + 2, 0, ldsA(BUF, 0)); }                             \
    if (VM == 4) { asm volatile("s_waitcnt vmcnt(4)" ::: "memory"); }       \
    else         { asm volatile("s_waitcnt vmcnt(0)" ::: "memory"); }       \
    PH_SYNC(); MMQ_N(1, 0); PH_END();                                       \
  }

template<int N, int K>
__global__ __launch_bounds__(512, 2) void gemm8n(
    const unsigned short* __restrict__ A,
    const unsigned short* __restrict__ W,
    const float* __restrict__ bias, float* __restrict__ Cf) {
  static_assert(K % 128 == 0, "NT must be even");
  constexpr int NT = K / 64;
  // LDS (ushort): A[buf] at buf*16384 (256x64 each); B[buf] at 32768+buf*8192
  // (128x64 each). 96 KiB total -> 1 block/CU, 8 waves.
  __shared__ unsigned short lds[49152];
  const int t = threadIdx.x;
  const int lane = t & 63;
  const int wave = t >> 6;
  const int wr = wave >> 2;   // M half (128 rows)
  const int wc = wave & 3;    // N quarter (32 cols)
  const int m0 = blockIdx.x * 256;
  const int n0 = blockIdx.y * 128;

  const int srow = t >> 3;
  const int scol = (((t & 7) ^ ((t >> 3) & 7)) * 8);   // 3-bit T2 key
  const unsigned short* gA = A + (size_t)(m0 + srow) * K + scol;
  const unsigned short* gB = W + (size_t)(n0 + srow) * K + scol;
  const int ldsw = wave * 512;

  auto ldsA = [&](int buf, int h) -> unsigned short* {
    return (unsigned short*)&lds[buf * 16384 + h * 8192 + ldsw];
  };
  auto ldsB = [&](int buf) -> unsigned short* {
    return (unsigned short*)&lds[32768 + buf * 8192 + ldsw];
  };
  auto stA = [&](int tile, int h, unsigned short* dst) {
    const unsigned short* s = gA + (size_t)(h * 128) * K + tile * 64;
    gld16(s, dst);
    gld16(s + (size_t)64 * K, dst + 4096);
  };
  auto stB = [&](int tile, unsigned short* dst) {
    const unsigned short* s = gB + (size_t)tile * 64;
    gld16(s, dst);
    gld16(s + (size_t)64 * K, dst + 4096);
  };

  const int swz = (lane & 7) << 3;
  const int ck0 = ((lane >> 4) * 8) ^ swz;
  const int ck1 = (32 + (lane >> 4) * 8) ^ swz;
  const int aB = wr * 8192 + (lane & 15) * 64;
  const int bB = wc * 2048 + (lane & 15) * 64;

  bf16x8 a[8];
  bf16x8 b[2][2];
  f32x4 acc[8][2] = {};

  // prologue: A0 full + B0 complete; {A1h0, B1} left in flight (A1h1 at ph1)
  stA(0, 0, ldsA(0, 0)); stA(0, 1, ldsA(0, 1));
  stB(0, ldsB(0));
  stA(1, 0, ldsA(1, 0));
  stB(1, ldsB(1));
  asm volatile("s_waitcnt vmcnt(4)" ::: "memory");
  __builtin_amdgcn_s_barrier();

  for (int tp = 0; tp < NT / 2 - 1; ++tp) {
    const int t0 = 2 * tp;
    TILE_N(t0, 0, 1, 1, 1, 4);
    TILE_N(t0 + 1, 1, 0, 1, 1, 4);
  }
  TILE_N(NT - 2, 0, 1, 1, 0, 0);
  TILE_N(NT - 1, 1, 0, 0, 0, 0);

  // epilogue: f32 residual RMW (64B-contiguous per 16 lanes)
  const int r0 = m0 + wr * 128 + ((lane >> 4) << 2);
  const int c0 = n0 + wc * 32 + (lane & 15);
#pragma unroll
  for (int mfg = 0; mfg < 8; ++mfg)
#pragma unroll
    for (int nfg = 0; nfg < 2; ++nfg) {
      const int col = c0 + nfg * 16;
      const float bv = bias[col];
#pragma unroll
      for (int r = 0; r < 4; ++r)
        Cf[(size_t)(r0 + mfg * 16 + r) * N + col] += acc[mfg][nfg][r] + bv;
    }
}

// ============ 256x256 8-phase GEMM (T2 3-bit swizzle + T3/T4 + T5) =========
#define RDA(BUF, MH)                                                        \
  _Pragma("unroll") for (int mf = 0; mf < 4; ++mf)                          \
  _Pragma("unroll") for (int kk = 0; kk < 2; ++kk)                          \
      a[mf * 2 + kk] = *(const bf16x8*)&lds[(BUF)*16384 + aB + (MH)*4096 +  \
                                            mf * 1024 + ((kk) ? ck1 : ck0)];

#define RDB0(BUF)                                                           \
  _Pragma("unroll") for (int q = 0; q < 2; ++q)                             \
  _Pragma("unroll") for (int kk = 0; kk < 2; ++kk)                          \
      b[0][q * 2 + kk] = *(const bf16x8*)&lds[(BUF)*16384 + bB + q * 1024 + \
                                              ((kk) ? ck1 : ck0)];

#define RDB1(BUF)                                                           \
  _Pragma("unroll") for (int q = 2; q < 4; ++q)                             \
  _Pragma("unroll") for (int kk = 0; kk < 2; ++kk)                          \
      b[1][(q & 1) * 2 + kk] =                                              \
          *(const bf16x8*)&lds[(BUF)*16384 + bB + q * 1024 +                \
                               ((kk) ? ck1 : ck0)];

#define MMQ(MH, NH)                                                         \
  _Pragma("unroll") for (int mf = 0; mf < 4; ++mf)                          \
  _Pragma("unroll") for (int nf = 0; nf < 2; ++nf)                          \
  _Pragma("unroll") for (int kk = 0; kk < 2; ++kk)                          \
      acc[(MH)*4 + mf][(NH)*2 + nf] = __builtin_amdgcn_mfma_f32_16x16x32_bf16( \
          a[mf * 2 + kk], b[NH][nf * 2 + kk], acc[(MH)*4 + mf][(NH)*2 + nf],  \
          0, 0, 0);

#define TILE_PHASES(TI, BUF, OBUF, S1, S2, VM)                              \
  {                                                                         \
    RDA(BUF, 0); RDB0(BUF);                                                 \
    if (S1) { stA((TI) + 1, 1, ldsA(OBUF, 1)); }                            \
    PH_SYNC(); MMQ(0, 0); PH_END();                                         \
    RDB1(BUF);                                                              \
    PH_SYNC(); MMQ(0, 1); PH_END();                                         \
    RDA(BUF, 1);                                                            \
    if (S2) { stB((TI) + 2, 0, ldsB(BUF, 0)); }                             \
    PH_SYNC(); MMQ(1, 1); PH_END();                                         \
    if (S2) { stB((TI) + 2, 1, ldsB(BUF, 1)); stA((TI) + 2, 0, ldsA(BUF, 0)); } \
    if (VM == 6) { asm volatile("s_waitcnt vmcnt(6)" ::: "memory"); }       \
    else         { asm volatile("s_waitcnt vmcnt(0)" ::: "memory"); }       \
    PH_SYNC(); MMQ(1, 0); PH_END();                                         \
  }

// EPI: 0 = f32 direct; 4 = gelu->bf16 (LDS-coalesced); 6 = interleaved
// z|htil + de-interleaved bf16 stores + FUSED scan1 -> Ac/Bc.
template<int N, int K, int EPI>
__global__ __launch_bounds__(512, 2) void gemm8p(
    const unsigned short* __restrict__ A,
    const unsigned short* __restrict__ W0,
    const float* __restrict__ bias0,
    float* __restrict__ Cf, unsigned short* __restrict__ Cb,
    unsigned short* __restrict__ Cb2,
    float* __restrict__ Ac, float* __restrict__ Bc) {
  static_assert(K % 128 == 0, "NT must be even");
  constexpr int NT = K / 64;
  __shared__ unsigned short lds[65536];   // 128 KiB; reused as [256][256]
  const int t = threadIdx.x;
  const int lane = t & 63;
  const int wave = t >> 6;
  const int wr = wave >> 2;
  const int wc = wave & 3;
  const int m0 = blockIdx.x * 256;
  const int n0 = blockIdx.y * 256;

  // --- staging addressing (pre-swizzled global source; linear LDS dest) ---
  const int srow = t >> 3;
  const int scol = (((t & 7) ^ ((t >> 3) & 7)) * 8);   // 3-bit T2 key
  const unsigned short* gA = A  + (size_t)(m0 + srow) * K + scol;
  const unsigned short* gB = W0 + (size_t)(n0 + srow) * K + scol;
  const int ldsw = wave * 512;

  auto ldsA = [&](int buf, int h) -> unsigned short* {
    return (unsigned short*)&lds[buf * 16384 + h * 8192 + ldsw];
  };
  auto ldsB = [&](int buf, int h) -> unsigned short* {
    return (unsigned short*)&lds[32768 + buf * 16384 + h * 8192 + ldsw];
  };
  auto stA = [&](int tile, int h, unsigned short* dst) {
    const unsigned short* s = gA + (size_t)(h * 128) * K + tile * 64;
    gld16(s, dst);
    gld16(s + (size_t)64 * K, dst + 4096);
  };
  auto stB = [&](int tile, int h, unsigned short* dst) {
    const unsigned short* s = gB + (size_t)(h * 128) * K + tile * 64;
    gld16(s, dst);
    gld16(s + (size_t)64 * K, dst + 4096);
  };

  // --- fragment read addressing (swizzled ds_read, 3-bit key = lane&7) ---
  const int swz = (lane & 7) << 3;
  const int ck0 = (((lane >> 4) * 8)) ^ swz;
  const int ck1 = (32 + ((lane >> 4) * 8)) ^ swz;
  const int aB = wr * 8192 + (lane & 15) * 64;
  const int bB = 32768 + (wc >> 1) * 8192 + (wc & 1) * 4096 + (lane & 15) * 64;

  bf16x8 a[8];
  bf16x8 b[2][4];
  f32x4 acc[8][4] = {};

  // --- prologue: A0,B0 full + {A1h0, B1h0, B1h1} left in flight ---
  stA(0, 0, ldsA(0, 0)); stA(0, 1, ldsA(0, 1));
  stB(0, 0, ldsB(0, 0)); stB(0, 1, ldsB(0, 1));
  stA(1, 0, ldsA(1, 0));
  stB(1, 0, ldsB(1, 0)); stB(1, 1, ldsB(1, 1));
  asm volatile("s_waitcnt vmcnt(6)" ::: "memory");
  __builtin_amdgcn_s_barrier();

  for (int tp = 0; tp < NT / 2 - 1; ++tp) {
    const int t0 = 2 * tp;
    TILE_PHASES(t0, 0, 1, 1, 1, 6);
    TILE_PHASES(t0 + 1, 1, 0, 1, 1, 6);
  }
  TILE_PHASES(NT - 2, 0, 1, 1, 0, 0);
  TILE_PHASES(NT - 1, 1, 0, 0, 0, 0);

  // --- epilogue ---
  const int r0l = wr * 128 + ((lane >> 4) << 2);
  const int c0l = wc * 64 + (lane & 15);
  if constexpr (EPI == 0) {
    const int r0 = m0 + r0l;
    const int c0 = n0 + c0l;
#pragma unroll
    for (int mfg = 0; mfg < 8; ++mfg)
#pragma unroll
      for (int nfg = 0; nfg < 4; ++nfg) {
        const int col = c0 + nfg * 16;
        const float bv = bias0[col];
#pragma unroll
        for (int r = 0; r < 4; ++r)
          Cf[(size_t)(r0 + mfg * 16 + r) * N + col] = acc[mfg][nfg][r] + bv;
      }
  } else {
    // activation -> swizzled LDS [256][256] -> coalesced stores
    const bool isz = ((lane & 1) == 0);   // EPI==6: even global col = z
#pragma unroll
    for (int mfg = 0; mfg < 8; ++mfg)
#pragma unroll
      for (int nfg = 0; nfg < 4; ++nfg) {
        const int col = c0l + nfg * 16;
        const float bv = bias0[n0 + col];
#pragma unroll
        for (int r = 0; r < 4; ++r) {
          const float v = acc[mfg][nfg][r] + bv;
          unsigned short o;
          if constexpr (EPI == 4) {
            o = f2bf(0.5f * v * (1.f + erff(v * 0.70710678118654752f)));
          } else {  // EPI == 6
            o = isz ? f2bf(1.f / (1.f + __expf(-v))) : f2bf(v);
          }
          const int rr = r0l + mfg * 16 + r;
          lds[rr * 256 + (col ^ (((rr >> 2) & 3) << 4))] = o;
        }
      }
    __syncthreads();
    if constexpr (EPI == 4) {
#pragma unroll
      for (int it = 0; it < 16; ++it) {
        const int flat = it * 512 + t;
        const int row = flat >> 5;
        const int ch = flat & 31;
        const float4 v = *(const float4*)&lds[row * 256 +
                                              ((ch * 8) ^ (((row >> 2) & 3) << 4))];
        *(float4*)&Cb[(size_t)(m0 + row) * N + n0 + ch * 8] = v;
      }
    } else {  // EPI == 6: de-interleave to Cb (z) / Cb2 (htil), width N/2
#pragma unroll
      for (int it = 0; it < 16; ++it) {
        const int flat = it * 512 + t;
        const int row = flat >> 5;
        const int ch = flat & 31;
        union { float4 v; unsigned u[4]; } q;
        q.v = *(const float4*)&lds[row * 256 +
                                   ((ch * 8) ^ (((row >> 2) & 3) << 4))];
        const ushort4 zz = make_ushort4(q.u[0] & 0xffff, q.u[1] & 0xffff,
                                        q.u[2] & 0xffff, q.u[3] & 0xffff);
        const ushort4 hh = make_ushort4(q.u[0] >> 16, q.u[1] >> 16,
                                        q.u[2] >> 16, q.u[3] >> 16);
        const size_t o = (size_t)(m0 + row) * (N / 2) + (n0 >> 1) + ch * 4;
        *(ushort4*)&Cb[o]  = zz;
        *(ushort4*)&Cb2[o] = hh;
      }
      // fused scan1: compose chunk-local (A,B) from the LDS bounce.
      if (t < 256) {
        const int lc = t >> 7;          // chunk half within tile
        const int lh = t & 127;         // local h
        float av = 1.f, bv = 0.f;
        const int s0 = lc * 128;
#pragma unroll 4
        for (int s = 0; s < CHS; ++s) {
          const int sr = s0 + s;
          const int c = (2 * lh) ^ (((sr >> 2) & 3) << 4);
          const unsigned w2 = *(const unsigned*)&lds[sr * 256 + c];
          const float zv = bf2f((unsigned short)(w2 & 0xffff));
          const float hv = bf2f((unsigned short)(w2 >> 16));
          const float aa = 1.f - zv;
          bv = aa * bv + zv * hv;
          av *= aa;
        }
        const int bidx = m0 / cS;
        const int ck = ((m0 & (cS - 1)) >> 7) + lc;
        const int hg = (n0 >> 1) + lh;
        const size_t so = ((size_t)bidx * NCH + ck) * cH + hg;
        Ac[so] = av;
        Bc[so] = bv;
      }
    }
  }
}

// fused scan2+scan3: per-thread prefix from chunk summaries, then replay;
// ck == NCH-1 threads emit h_next. R15: hp granularity 2 -> 256 blocks
// (full CU coverage for this latency/BW-bound kernel); arithmetic identical.
__global__ __launch_bounds__(256) void scan23_k(const unsigned short* __restrict__ z,
    unsigned short* __restrict__ ht, const float* __restrict__ Ac,
    const float* __restrict__ Bc, const float* __restrict__ h_prev,
    float* __restrict__ hn, int l) {
  const int tid = blockIdx.x * 256 + threadIdx.x;   // cB*NCH*(cH/2)
  const int hp = (tid & (cH / 2 - 1)) * 2;
  const int ck = (tid / (cH / 2)) & (NCH - 1);
  const int b = tid / ((cH / 2) * NCH);
  const size_t hoff = ((size_t)b * cL + l) * cH + hp;
  const float2 h0 = *(const float2*)&h_prev[hoff];
  float r0 = h0.x, r1 = h0.y;
  for (int c = 0; c < ck; ++c) {           // block-uniform trip count
    const size_t so = ((size_t)b * NCH + c) * cH + hp;
    const float2 av = *(const float2*)&Ac[so];
    const float2 bv = *(const float2*)&Bc[so];
    r0 = av.x * r0 + bv.x;
    r1 = av.y * r1 + bv.y;
  }
  const size_t base = ((size_t)b * cS + (size_t)ck * CHS) * cH + hp;
#pragma unroll 4
  for (int s = 0; s < CHS; ++s) {
    const unsigned zz = *(const unsigned*)&z[base + (size_t)s * cH];
    const unsigned hh = *(const unsigned*)&ht[base + (size_t)s * cH];
    const float z0 = bf2f((unsigned short)(zz & 0xffff));
    const float z1 = bf2f((unsigned short)(zz >> 16));
    const float t0 = bf2f((unsigned short)(hh & 0xffff));
    const float t1 = bf2f((unsigned short)(hh >> 16));
    r0 = (1.f - z0) * r0 + z0 * t0;
    r1 = (1.f - z1) * r1 + z1 * t1;
    *(unsigned*)&ht[base + (size_t)s * cH] =
        (unsigned)f2bf(r0) | ((unsigned)f2bf(r1) << 16);
  }
  if (ck == NCH - 1) *(float2*)&hn[hoff] = make_float2(r0, r1);
}

extern "C" void kernel_launch(void* const* d_in, const int* in_sizes, int n_in,
                              void* d_out, int out_size, void* d_ws, size_t ws_size,
                              hipStream_t stream) {
  (void)in_sizes; (void)n_in; (void)out_size; (void)ws_size;
  const int*   x      = (const int*)d_in[0];
  const float* h_prev = (const float*)d_in[1];
  const float* emb    = (const float*)d_in[2];
  const float* cdw_w  = (const float*)d_in[3];
  const float* cdw_b  = (const float*)d_in[4];
  const float* cpw_w  = (const float*)d_in[5];
  const float* cpw_b  = (const float*)d_in[6];
  const float* n1w    = (const float*)d_in[7];
  const float* wzp    = (const float*)d_in[8];
  const float* bzp    = (const float*)d_in[9];
  const float* whp    = (const float*)d_in[10];
  const float* bhp    = (const float*)d_in[11];
  const float* wop    = (const float*)d_in[12];
  const float* bop    = (const float*)d_in[13];
  const float* n2w    = (const float*)d_in[14];
  const float* f1wp   = (const float*)d_in[15];
  const float* f1bp   = (const float*)d_in[16];
  const float* f2wp   = (const float*)d_in[17];
  const float* f2bp   = (const float*)d_in[18];
  const float* nw     = (const float*)d_in[19];
  const float* owp    = (const float*)d_in[20];
  const float* obp    = (const float*)d_in[21];

  float* out_main = (float*)d_out;                  // (B,S,H) f32
  float* out_hn   = out_main + (size_t)cM * cH;     // (B,L,H) f32

  char* p = (char*)d_ws;
  auto alloc = [&](size_t bytes) {
    char* r = p; p += (bytes + 255) & ~(size_t)255; return r;
  };
  float*          xe = (float*)alloc((size_t)cM * cD * 4);
  unsigned short* xn = (unsigned short*)alloc((size_t)cM * cD * 2);
  unsigned short* zb = (unsigned short*)alloc((size_t)cM * cH * 2);
  unsigned short* hb = (unsigned short*)alloc((size_t)cM * cH * 2);
  float* Ac = (float*)alloc((size_t)cB * NCH * cH * 4);
  float* Bc = (float*)alloc((size_t)cB * NCH * cH * 4);
  // all-layer bf16 weights (hoisted conversion)
  unsigned short* w_pw = (unsigned short*)alloc((size_t)cL * cD * cD * 2);
  unsigned short* w_zh = (unsigned short*)alloc((size_t)cL * 2 * cH * cD * 2);
  float*          bzh  = (float*)alloc((size_t)cL * 2 * cH * 4);
  unsigned short* w_o  = (unsigned short*)alloc((size_t)cL * cD * cH * 2);
  unsigned short* w_f1 = (unsigned short*)alloc((size_t)cL * cH * cD * 2);
  unsigned short* w_f2 = (unsigned short*)alloc((size_t)cL * cD * cH * 2);
  unsigned short* w_ow = (unsigned short*)alloc((size_t)cH * cD * 2);

  // merged weight prep: 3 dispatches total
  {
    constexpr size_t total = (size_t)cL * cD * cD + 3 * (size_t)cL * cD * cH +
                             (size_t)cH * cD;
    wcvt_k<<<dim3((unsigned)(total / 1024)), 256, 0, stream>>>(
        cpw_w, w_pw, wop, w_o, f1wp, w_f1, f2wp, w_f2, owp, w_ow);
    cvti2_k<<<dim3(cL * cH * cD / 1024), 256, 0, stream>>>(wzp, whp, w_zh);
    biasi2_k<<<dim3(cL * cH / 256), 256, 0, stream>>>(bzp, bhp, bzh);
  }

  embed_k<<<cM, 256, 0, stream>>>(x, emb, xe);

  for (int l = 0; l < cL; ++l) {
    const size_t oDD = (size_t)l * cD * cD, oHD = (size_t)l * cH * cD;

    // conv block: xe += pw(dwconv(xe)) + b
    dwconv_k<<<cM, 256, 0, stream>>>(xe, cdw_w + (size_t)l * cD * 3,
                                     cdw_b + (size_t)l * cD, xn);
    gemm8n<cD, cD><<<dim3(cM / 256, cD / 128), 512, 0, stream>>>(
        xn, w_pw + oDD, cpw_b + (size_t)l * cD, xe);

    // minGRU block: interleaved z|htil GEMM with fused scan1
    rmsnorm_k<<<cM, 256, 0, stream>>>(xe, n1w + (size_t)l * cD, xn);
    gemm8p<2 * cH, cD, 6><<<dim3(cM / 256, 2 * cH / 256), 512, 0, stream>>>(
        xn, w_zh + (size_t)l * 2 * cH * cD, bzh + (size_t)l * 2 * cH,
        nullptr, zb, hb, Ac, Bc);
    scan23_k<<<cB * NCH * (cH / 2) / 256, 256, 0, stream>>>(zb, hb, Ac, Bc,
                                                            h_prev, out_hn, l);
    gemm8n<cD, cH><<<dim3(cM / 256, cD / 128), 512, 0, stream>>>(
        hb, w_o + oHD, bop + (size_t)l * cD, xe);

    // FFN block
    rmsnorm_k<<<cM, 256, 0, stream>>>(xe, n2w + (size_t)l * cD, xn);
    gemm8p<cH, cD, 4><<<dim3(cM / 256, cH / 256), 512, 0, stream>>>(
        xn, w_f1 + oHD, f1bp + (size_t)l * cH, nullptr, zb, nullptr,
        nullptr, nullptr);
    gemm8n<cD, cH><<<dim3(cM / 256, cD / 128), 512, 0, stream>>>(
        zb, w_f2 + oHD, f2bp + (size_t)l * cD, xe);
  }

  rmsnorm_k<<<cM, 256, 0, stream>>>(xe, nw, xn);
  gemm8p<cH, cD, 0><<<dim3(cM / 256, cH / 256), 512, 0, stream>>>(
      xn, w_ow, obp, out_main, nullptr, nullptr, nullptr, nullptr);
}